// Round 1
// baseline (728.240 us; speedup 1.0000x reference)
//
#include <hip/hip_runtime.h>
#include <hip/hip_bf16.h>
#include <math.h>

#define S_  1024
#define E_  2560
#define H_  32
#define D_  80
#define E3_ 7680
#define M_  2048   // B*S
#define QK_ 5120   // packed Q|K row width in ws

typedef short bf16x8 __attribute__((ext_vector_type(8)));
typedef float f32x4  __attribute__((ext_vector_type(4)));

static __device__ __forceinline__ float bf2f(unsigned short u) {
    unsigned int i = ((unsigned int)u) << 16;
    float f; __builtin_memcpy(&f, &i, 4); return f;
}
static __device__ __forceinline__ unsigned short f2bf(float f) {
    unsigned int i; __builtin_memcpy(&i, &f, 4);
    i += 0x7fffu + ((i >> 16) & 1u);
    return (unsigned short)(i >> 16);
}

// ---------- pre-pass: fp32 -> bf16 flat convert ----------
__global__ __launch_bounds__(256) void cvt_bf16_kernel(
    const float* __restrict__ in, unsigned short* __restrict__ out, int n8)
{
    int i = (blockIdx.x * 256 + threadIdx.x);
    if (i >= n8) return;
    const float* p = in + (size_t)i * 8;
    float4 a = *(const float4*)p;
    float4 b = *(const float4*)(p + 4);
    union { uint4 v; unsigned short s[8]; } o;
    o.s[0]=f2bf(a.x); o.s[1]=f2bf(a.y); o.s[2]=f2bf(a.z); o.s[3]=f2bf(a.w);
    o.s[4]=f2bf(b.x); o.s[5]=f2bf(b.y); o.s[6]=f2bf(b.z); o.s[7]=f2bf(b.w);
    *(uint4*)(out + (size_t)i * 8) = o.v;
}

// ---------- pre-pass: fp32 [R][C] -> bf16 [C][R] transpose-convert ----------
__global__ __launch_bounds__(256) void transpose_bf16_kernel(
    const float* __restrict__ in, unsigned short* __restrict__ out, int R, int C)
{
    const int t = threadIdx.x;
    const int r0 = blockIdx.y * 64, c0 = blockIdx.x * 64;
    const int r4 = (t >> 4) * 4;
    const int c4 = (t & 15) * 4;
    float4 rows[4];
#pragma unroll
    for (int i = 0; i < 4; ++i)
        rows[i] = *(const float4*)&in[(size_t)(r0 + r4 + i) * C + c0 + c4];
    const float rv[4][4] = {
        {rows[0].x, rows[0].y, rows[0].z, rows[0].w},
        {rows[1].x, rows[1].y, rows[1].z, rows[1].w},
        {rows[2].x, rows[2].y, rows[2].z, rows[2].w},
        {rows[3].x, rows[3].y, rows[3].z, rows[3].w}};
#pragma unroll
    for (int j = 0; j < 4; ++j) {
        ushort4 o;
        o.x = f2bf(rv[0][j]); o.y = f2bf(rv[1][j]);
        o.z = f2bf(rv[2][j]); o.w = f2bf(rv[3][j]);
        *(ushort4*)&out[(size_t)(c0 + c4 + j) * R + r0 + r4] = o;
    }
}

// ---------- MFMA GEMM (round-5 + XCD-chunked block swizzle) ----------
template <bool A_F32, bool OUT_F32>
__global__ __launch_bounds__(256, 2) void mfma_gemm_kernel(
    const void* __restrict__ A, int lda,
    const unsigned short* __restrict__ Wt,
    const float* __restrict__ bias,
    void* __restrict__ dst0, int sd0,
    void* __restrict__ dst1, int sd1, int ncut,
    int K)
{
    __shared__ unsigned short As[128 * 40];
    __shared__ unsigned short Bs[128 * 40];

    const int t    = threadIdx.x;
    // XCD-aware bijective swizzle: consecutive linear ids round-robin over 8 XCDs;
    // remap so each XCD owns a contiguous chunk (A-panel stays L2-resident).
    // Both grids (960, 320) are divisible by 8.
    const int gx  = gridDim.x;
    const int nwg = gx * gridDim.y;
    int lin = blockIdx.y * gx + blockIdx.x;
    lin = (lin & 7) * (nwg >> 3) + (lin >> 3);
    const int m0   = (lin / gx) * 128;
    const int n0   = (lin % gx) * 128;
    const int lane = t & 63, wave = t >> 6;
    const int quad = lane >> 4, l15 = lane & 15;
    const int mw   = (wave >> 1) * 64;
    const int nw   = (wave & 1) * 64;
    const int r    = t >> 1;
    const int hh   = (t & 1) * 16;

    f32x4 acc[4][4];
#pragma unroll
    for (int i = 0; i < 4; ++i)
#pragma unroll
        for (int j = 0; j < 4; ++j) acc[i][j] = (f32x4){0.f, 0.f, 0.f, 0.f};

    const size_t a_base = (size_t)(m0 + r) * lda + hh;
    const unsigned short* bp = Wt + (size_t)(n0 + r) * K + hh;

    for (int k0 = 0; k0 < K; k0 += 32) {
        uint4 a0, a1;
        if (A_F32) {
            const float* ap = (const float*)A + a_base + k0;
            float4 f0 = *(const float4*)ap;
            float4 f1 = *(const float4*)(ap + 4);
            float4 f2 = *(const float4*)(ap + 8);
            float4 f3 = *(const float4*)(ap + 12);
            union { uint4 v; unsigned short s[8]; } u0, u1;
            u0.s[0]=f2bf(f0.x); u0.s[1]=f2bf(f0.y); u0.s[2]=f2bf(f0.z); u0.s[3]=f2bf(f0.w);
            u0.s[4]=f2bf(f1.x); u0.s[5]=f2bf(f1.y); u0.s[6]=f2bf(f1.z); u0.s[7]=f2bf(f1.w);
            u1.s[0]=f2bf(f2.x); u1.s[1]=f2bf(f2.y); u1.s[2]=f2bf(f2.z); u1.s[3]=f2bf(f2.w);
            u1.s[4]=f2bf(f3.x); u1.s[5]=f2bf(f3.y); u1.s[6]=f2bf(f3.z); u1.s[7]=f2bf(f3.w);
            a0 = u0.v; a1 = u1.v;
        } else {
            const unsigned short* ap = (const unsigned short*)A + a_base + k0;
            a0 = *(const uint4*)ap;
            a1 = *(const uint4*)(ap + 8);
        }
        uint4 b0 = *(const uint4*)(bp + k0);
        uint4 b1 = *(const uint4*)(bp + k0 + 8);
        __syncthreads();
        *(uint4*)&As[r * 40 + hh]     = a0;
        *(uint4*)&As[r * 40 + hh + 8] = a1;
        *(uint4*)&Bs[r * 40 + hh]     = b0;
        *(uint4*)&Bs[r * 40 + hh + 8] = b1;
        __syncthreads();

        bf16x8 af[4], bfr[4];
#pragma unroll
        for (int i = 0; i < 4; ++i)
            af[i] = *(const bf16x8*)&As[(mw + i * 16 + l15) * 40 + quad * 8];
#pragma unroll
        for (int j = 0; j < 4; ++j)
            bfr[j] = *(const bf16x8*)&Bs[(nw + j * 16 + l15) * 40 + quad * 8];
#pragma unroll
        for (int i = 0; i < 4; ++i)
#pragma unroll
            for (int j = 0; j < 4; ++j)
                acc[i][j] = __builtin_amdgcn_mfma_f32_16x16x32_bf16(af[i], bfr[j], acc[i][j], 0, 0, 0);
    }

#pragma unroll
    for (int j = 0; j < 4; ++j) {
        const int col = n0 + nw + j * 16 + l15;
        const float bv = bias[col];
        if (OUT_F32) {
            float* dst = (float*)dst0;
#pragma unroll
            for (int i = 0; i < 4; ++i) {
                const int rowb = m0 + mw + i * 16 + quad * 4;
#pragma unroll
                for (int g = 0; g < 4; ++g)
                    dst[(size_t)(rowb + g) * sd0 + col] = acc[i][j][g] + bv;
            }
        } else {
            unsigned short* dst; int sd, cc;
            if (col < ncut) { dst = (unsigned short*)dst0; sd = sd0; cc = col; }
            else            { dst = (unsigned short*)dst1; sd = sd1; cc = col - ncut; }
#pragma unroll
            for (int i = 0; i < 4; ++i) {
                const int rowb = m0 + mw + i * 16 + quad * 4;
#pragma unroll
                for (int g = 0; g < 4; ++g)
                    dst[(size_t)(rowb + g) * sd + cc] = f2bf(acc[i][j][g] + bv);
            }
        }
    }
}

// ---------- MFMA fused attention ----------
// Round-6 changes vs round-5:
//   * __launch_bounds__(256,4): LDS 35.3KB -> 4 blocks/CU (was 2) for latency hiding.
//   * T14 async-stage: next K/V tile global loads issued into registers BEFORE
//     computing the current tile; LDS writes happen after the barrier.
//   * V^T staging remapped kg-inner: LDS write banks cover all 32 exactly
//     (was ~8-10-way conflict with dg-inner mapping).
//   * XCD-chunked block swizzle: each XCD gets 8 consecutive bh -> K/V tiles
//     (2.5MB) stay resident in that XCD's 4MB L2.
__global__ __launch_bounds__(256, 4) void attn_mfma_kernel(
    unsigned short* __restrict__ qk,         // [2048][5120] bf16: Q [0,2560), K [2560,5120)
    const unsigned short* __restrict__ vsrc, // [2048][2560] bf16 (parked in d_out)
    const float* __restrict__ gmats,
    const float* __restrict__ gphases,
    const float* __restrict__ gamps,
    const float* __restrict__ qphase,
    const float* __restrict__ is_ptr)
{
    __shared__ unsigned short Ks[64 * 104]; // Q tile (prologue) then K tiles; [row][d], pad d 80..96 = 0
    __shared__ unsigned short Vt[80 * 72];  // V^T [d][kj]
    __shared__ unsigned short Ps[64 * 72];  // P [q][kj] bf16
    __shared__ float cs[240];               // coeffs [3][80]

    const int t    = threadIdx.x;
    const int wave = t >> 6, lane = t & 63;
    const int quad = lane >> 4, l15 = lane & 15;
    // bijective XCD swizzle over 1024 blocks (8 XCDs x 128 chunks)
    const int lin0 = blockIdx.x;
    const int lin  = ((lin0 & 7) << 7) | (lin0 >> 3);
    const int qt = lin & 15;
    const int bh = lin >> 4;
    const int h  = bh & 31;
    const int b  = bh >> 5;

    const float scale = 0.111803398874989485f;   // 1/sqrt(80)
    const float c2    = scale * scale * is_ptr[0] * (1.0f / 3.0f);
    const float cosph = cosf(qphase[h]);

    if (t < 240) {
        int g = t / 80;
        float r0 = gmats[g*4+0] + gmats[g*4+1];
        float r1 = gmats[g*4+2] + gmats[g*4+3];
        cs[t] = (cosf(gphases[t]) * r0 + sinf(gphases[t]) * r1) * gamps[t];
    }

    const int srow = t >> 2;          // staging row 0..63 (wave w stages rows 16w..16w+15)
    const int scg  = (t & 3) * 20;    // staging col group (20 bf16)

    // V staging mapping (kg-inner for conflict-free LDS writes):
    // item A (all t): kj-group vkg = t&15, d-group vdg = t>>4   (dg 0..15)
    // item B (t<64):  kj-group vkg = t&15, d-group 16 + (t>>4)  (dg 16..19)
    const int vkg  = t & 15;
    const int vdg0 = t >> 4;

    {   // stage Q tile into Ks + zero the d-pad [80,96)
        const unsigned short* qp = qk + (size_t)(b * S_ + qt * 64 + srow) * QK_ + h * D_ + scg;
#pragma unroll
        for (int u = 0; u < 5; ++u)
            *(ushort4*)&Ks[srow * 104 + scg + 4 * u] = *(const ushort4*)(qp + 4 * u);
        *(ushort4*)&Ks[srow * 104 + 80 + (t & 3) * 4] = (ushort4){0, 0, 0, 0};
    }
    __syncthreads();   // cs + Q visible

    // ---- prefetch tile 0 into registers (overlaps afq/afg build) ----
    ushort4 kpre[5];
    ushort4 vpre[8];
    {
        const unsigned short* kp = qk + (size_t)(b * S_ + srow) * QK_ + E_ + h * D_ + scg;
#pragma unroll
        for (int u = 0; u < 5; ++u) kpre[u] = *(const ushort4*)(kp + 4 * u);
        const unsigned short* vb = vsrc + (size_t)(b * S_) * E_ + h * D_;
#pragma unroll
        for (int i = 0; i < 4; ++i)
            vpre[i] = *(const ushort4*)(vb + (size_t)(vkg * 4 + i) * E_ + vdg0 * 4);
        if (t < 64) {
#pragma unroll
            for (int i = 0; i < 4; ++i)
                vpre[4 + i] = *(const ushort4*)(vb + (size_t)(vkg * 4 + i) * E_ + 64 + vdg0 * 4);
        }
    }

    // A-fragments: base Q + 3 coefficient-scaled variants (persist across k-tiles)
    bf16x8 afq[3], afg[3][3];
#pragma unroll
    for (int kc = 0; kc < 3; ++kc)
        afq[kc] = *(const bf16x8*)&Ks[(wave * 16 + l15) * 104 + quad * 8 + kc * 32];
#pragma unroll
    for (int g = 0; g < 3; ++g)
#pragma unroll
        for (int kc = 0; kc < 3; ++kc)
#pragma unroll
            for (int j = 0; j < 8; ++j) {
                int d = kc * 32 + quad * 8 + j;
                float c = (d < 80) ? cs[g * 80 + d] : 0.f;
                afg[g][kc][j] = (short)f2bf(bf2f((unsigned short)afq[kc][j]) * c);
            }

    f32x4 Ov[5];
#pragma unroll
    for (int nf = 0; nf < 5; ++nf) Ov[nf] = (f32x4){0.f, 0.f, 0.f, 0.f};
    float m_r[4] = {-INFINITY, -INFINITY, -INFINITY, -INFINITY};
    float l_r[4] = {0.f, 0.f, 0.f, 0.f};

    for (int kt = 0; kt < 16; ++kt) {
        __syncthreads();   // prev iter's Ks/Vt/Ps reads complete (iter0: Q-frag reads done)

        // ---- write prefetched K tile [kj][d] into Ks (pad stays 0) ----
#pragma unroll
        for (int u = 0; u < 5; ++u)
            *(ushort4*)&Ks[srow * 104 + scg + 4 * u] = kpre[u];

        // ---- write prefetched V^T [d][kj] via 4x4 in-register transpose ----
        {
            const unsigned short rm[4][4] = {
                {vpre[0].x, vpre[0].y, vpre[0].z, vpre[0].w},
                {vpre[1].x, vpre[1].y, vpre[1].z, vpre[1].w},
                {vpre[2].x, vpre[2].y, vpre[2].z, vpre[2].w},
                {vpre[3].x, vpre[3].y, vpre[3].z, vpre[3].w}};
#pragma unroll
            for (int j = 0; j < 4; ++j) {
                ushort4 w = {rm[0][j], rm[1][j], rm[2][j], rm[3][j]};
                *(ushort4*)&Vt[(vdg0 * 4 + j) * 72 + vkg * 4] = w;
            }
        }
        if (t < 64) {
            const unsigned short rm[4][4] = {
                {vpre[4].x, vpre[4].y, vpre[4].z, vpre[4].w},
                {vpre[5].x, vpre[5].y, vpre[5].z, vpre[5].w},
                {vpre[6].x, vpre[6].y, vpre[6].z, vpre[6].w},
                {vpre[7].x, vpre[7].y, vpre[7].z, vpre[7].w}};
#pragma unroll
            for (int j = 0; j < 4; ++j) {
                ushort4 w = {rm[0][j], rm[1][j], rm[2][j], rm[3][j]};
                *(ushort4*)&Vt[(64 + vdg0 * 4 + j) * 72 + vkg * 4] = w;
            }
        }
        __syncthreads();

        // ---- issue next tile's global loads; latency hides under compute ----
        if (kt < 15) {
            const unsigned short* kp = qk + (size_t)(b * S_ + (kt + 1) * 64 + srow) * QK_ + E_ + h * D_ + scg;
#pragma unroll
            for (int u = 0; u < 5; ++u) kpre[u] = *(const ushort4*)(kp + 4 * u);
            const unsigned short* vb = vsrc + (size_t)(b * S_ + (kt + 1) * 64) * E_ + h * D_;
#pragma unroll
            for (int i = 0; i < 4; ++i)
                vpre[i] = *(const ushort4*)(vb + (size_t)(vkg * 4 + i) * E_ + vdg0 * 4);
            if (t < 64) {
#pragma unroll
                for (int i = 0; i < 4; ++i)
                    vpre[4 + i] = *(const ushort4*)(vb + (size_t)(vkg * 4 + i) * E_ + 64 + vdg0 * 4);
            }
        }

        // ---- score MFMAs: 4 variants x 4 n-frags x 3 k-chunks ----
        f32x4 sacc[4][4];
#pragma unroll
        for (int v = 0; v < 4; ++v)
#pragma unroll
            for (int nf = 0; nf < 4; ++nf) sacc[v][nf] = (f32x4){0.f, 0.f, 0.f, 0.f};
#pragma unroll
        for (int kc = 0; kc < 3; ++kc) {
            bf16x8 bk[4];
#pragma unroll
            for (int nf = 0; nf < 4; ++nf)
                bk[nf] = *(const bf16x8*)&Ks[(nf * 16 + l15) * 104 + quad * 8 + kc * 32];
#pragma unroll
            for (int nf = 0; nf < 4; ++nf)
                sacc[0][nf] = __builtin_amdgcn_mfma_f32_16x16x32_bf16(afq[kc], bk[nf], sacc[0][nf], 0, 0, 0);
#pragma unroll
            for (int g = 0; g < 3; ++g)
#pragma unroll
                for (int nf = 0; nf < 4; ++nf)
                    sacc[1+g][nf] = __builtin_amdgcn_mfma_f32_16x16x32_bf16(afg[g][kc], bk[nf], sacc[1+g][nf], 0, 0, 0);
        }

        // ---- combine + online softmax (C layout: row=quad*4+r, col=l15+16nf) ----
        float p[4][4];   // [nf][r]
        float mx[4] = {-INFINITY, -INFINITY, -INFINITY, -INFINITY};
#pragma unroll
        for (int nf = 0; nf < 4; ++nf)
#pragma unroll
            for (int r = 0; r < 4; ++r) {
                float s0 = sacc[1][nf][r], s1 = sacc[2][nf][r], s2 = sacc[3][nf][r];
                float s = sacc[0][nf][r] * scale + (s0 * s1 + s0 * s2 + s1 * s2) * c2;
                p[nf][r] = s;
                mx[r] = fmaxf(mx[r], s);
            }
#pragma unroll
        for (int r = 0; r < 4; ++r) {
            mx[r] = fmaxf(mx[r], __shfl_xor(mx[r], 1));
            mx[r] = fmaxf(mx[r], __shfl_xor(mx[r], 2));
            mx[r] = fmaxf(mx[r], __shfl_xor(mx[r], 4));
            mx[r] = fmaxf(mx[r], __shfl_xor(mx[r], 8));
        }
        float alpha[4];
#pragma unroll
        for (int r = 0; r < 4; ++r) {
            float m_new = fmaxf(m_r[r], mx[r]);
            alpha[r] = __expf(m_r[r] - m_new);
            m_r[r] = m_new;
        }
#pragma unroll
        for (int nf = 0; nf < 4; ++nf)
#pragma unroll
            for (int r = 0; r < 4; ++r)
                p[nf][r] = __expf(p[nf][r] - m_r[r]);
#pragma unroll
        for (int r = 0; r < 4; ++r) {
            float s = p[0][r] + p[1][r] + p[2][r] + p[3][r];
            s += __shfl_xor(s, 1);
            s += __shfl_xor(s, 2);
            s += __shfl_xor(s, 4);
            s += __shfl_xor(s, 8);
            l_r[r] = l_r[r] * alpha[r] + s;
        }

        // ---- write P (bf16) to LDS; own-wave rows only ----
#pragma unroll
        for (int nf = 0; nf < 4; ++nf)
#pragma unroll
            for (int r = 0; r < 4; ++r)
                Ps[(wave * 16 + quad * 4 + r) * 72 + l15 + 16 * nf] = f2bf(p[nf][r]);
        __asm__ volatile("s_waitcnt lgkmcnt(0)" ::: "memory");

        // ---- O rescale + PV MFMAs ----
#pragma unroll
        for (int nf = 0; nf < 5; ++nf)
#pragma unroll
            for (int r = 0; r < 4; ++r) Ov[nf][r] *= alpha[r];

        bf16x8 ap[2];
#pragma unroll
        for (int kc = 0; kc < 2; ++kc)
            ap[kc] = *(const bf16x8*)&Ps[(wave * 16 + l15) * 72 + quad * 8 + kc * 32];
#pragma unroll
        for (int nf = 0; nf < 5; ++nf)
#pragma unroll
            for (int kc = 0; kc < 2; ++kc) {
                bf16x8 bv = *(const bf16x8*)&Vt[(nf * 16 + l15) * 72 + quad * 8 + kc * 32];
                Ov[nf] = __builtin_amdgcn_mfma_f32_16x16x32_bf16(ap[kc], bv, Ov[nf], 0, 0, 0);
            }
    }

    // ---- epilogue: O * cos(phase)/l -> Q section of qk (bf16) ----
    float inv[4];
#pragma unroll
    for (int r = 0; r < 4; ++r) inv[r] = cosph / l_r[r];
#pragma unroll
    for (int nf = 0; nf < 5; ++nf)
#pragma unroll
        for (int r = 0; r < 4; ++r)
            qk[(size_t)(b * S_ + qt * 64 + wave * 16 + quad * 4 + r) * QK_ + h * D_ + nf * 16 + l15]
                = f2bf(Ov[nf][r] * inv[r]);
}

extern "C" void kernel_launch(void* const* d_in, const int* in_sizes, int n_in,
                              void* d_out, int out_size, void* d_ws, size_t ws_size,
                              hipStream_t stream) {
    (void)in_sizes; (void)n_in; (void)out_size; (void)ws_size;
    const float* hidden  = (const float*)d_in[0];
    const float* Wqkv    = (const float*)d_in[1];
    const float* bqkv    = (const float*)d_in[2];
    const float* Wproj   = (const float*)d_in[3];
    const float* bproj   = (const float*)d_in[4];
    const float* gmats   = (const float*)d_in[5];
    const float* gphases = (const float*)d_in[6];
    const float* gamps   = (const float*)d_in[7];
    const float* qphase  = (const float*)d_in[8];
    const float* is_ptr  = (const float*)d_in[9];

    // ws layout (70.8 MB): qk_ws 21.0 MB | h_bf16 10.5 MB | Wt 39.3 MB (reused for Wproj_t)
    unsigned short* qk_ws  = (unsigned short*)d_ws;
    unsigned short* h_bf16 = (unsigned short*)((char*)d_ws + (size_t)M_ * QK_ * 2);
    unsigned short* Wt     = (unsigned short*)((char*)d_ws + (size_t)M_ * QK_ * 2 + (size_t)M_ * E_ * 2);
    unsigned short* v_buf  = (unsigned short*)d_out;   // V bf16 parked in d_out (consumed by attn)

    dim3 blk(256);
    cvt_bf16_kernel<<<dim3((M_ * E_ / 8 + 255) / 256), blk, 0, stream>>>(hidden, h_bf16, M_ * E_ / 8);
    transpose_bf16_kernel<<<dim3(E3_/64, E_/64), blk, 0, stream>>>(Wqkv, Wt, E_, E3_);
    mfma_gemm_kernel<false, false><<<dim3(E3_/128, M_/128), blk, 0, stream>>>(
        h_bf16, E_, Wt, bqkv, qk_ws, QK_, v_buf, E_, QK_, E_);
    attn_mfma_kernel<<<dim3(2 * H_ * (S_/64)), blk, 0, stream>>>(
        qk_ws, v_buf, gmats, gphases, gamps, qphase, is_ptr);
    transpose_bf16_kernel<<<dim3(E_/64, E_/64), blk, 0, stream>>>(Wproj, Wt, E_, E_);
    mfma_gemm_kernel<false, true><<<dim3(E_/128, M_/128), blk, 0, stream>>>(
        qk_ws, QK_, Wt, bproj, d_out, E_, d_out, E_, E_, E_);
}

// Round 2
// 643.709 us; speedup vs baseline: 1.1313x; 1.1313x over previous
//
#include <hip/hip_runtime.h>
#include <hip/hip_bf16.h>
#include <math.h>

#define S_  1024
#define E_  2560
#define H_  32
#define D_  80
#define E3_ 7680
#define M_  2048   // B*S
#define QK_ 5120   // packed Q|K row width in ws

typedef short bf16x8 __attribute__((ext_vector_type(8)));
typedef float f32x4  __attribute__((ext_vector_type(4)));

static __device__ __forceinline__ float bf2f(unsigned short u) {
    unsigned int i = ((unsigned int)u) << 16;
    float f; __builtin_memcpy(&f, &i, 4); return f;
}
static __device__ __forceinline__ unsigned short f2bf(float f) {
    unsigned int i; __builtin_memcpy(&i, &f, 4);
    i += 0x7fffu + ((i >> 16) & 1u);
    return (unsigned short)(i >> 16);
}

// ---------- pre-pass: fp32 -> bf16 flat convert ----------
__global__ __launch_bounds__(256) void cvt_bf16_kernel(
    const float* __restrict__ in, unsigned short* __restrict__ out, int n8)
{
    int i = (blockIdx.x * 256 + threadIdx.x);
    if (i >= n8) return;
    const float* p = in + (size_t)i * 8;
    float4 a = *(const float4*)p;
    float4 b = *(const float4*)(p + 4);
    union { uint4 v; unsigned short s[8]; } o;
    o.s[0]=f2bf(a.x); o.s[1]=f2bf(a.y); o.s[2]=f2bf(a.z); o.s[3]=f2bf(a.w);
    o.s[4]=f2bf(b.x); o.s[5]=f2bf(b.y); o.s[6]=f2bf(b.z); o.s[7]=f2bf(b.w);
    *(uint4*)(out + (size_t)i * 8) = o.v;
}

// ---------- pre-pass: fp32 [R][C] -> bf16 [C][R] transpose-convert ----------
__global__ __launch_bounds__(256) void transpose_bf16_kernel(
    const float* __restrict__ in, unsigned short* __restrict__ out, int R, int C)
{
    const int t = threadIdx.x;
    const int r0 = blockIdx.y * 64, c0 = blockIdx.x * 64;
    const int r4 = (t >> 4) * 4;
    const int c4 = (t & 15) * 4;
    float4 rows[4];
#pragma unroll
    for (int i = 0; i < 4; ++i)
        rows[i] = *(const float4*)&in[(size_t)(r0 + r4 + i) * C + c0 + c4];
    const float rv[4][4] = {
        {rows[0].x, rows[0].y, rows[0].z, rows[0].w},
        {rows[1].x, rows[1].y, rows[1].z, rows[1].w},
        {rows[2].x, rows[2].y, rows[2].z, rows[2].w},
        {rows[3].x, rows[3].y, rows[3].z, rows[3].w}};
#pragma unroll
    for (int j = 0; j < 4; ++j) {
        ushort4 o;
        o.x = f2bf(rv[0][j]); o.y = f2bf(rv[1][j]);
        o.z = f2bf(rv[2][j]); o.w = f2bf(rv[3][j]);
        *(ushort4*)&out[(size_t)(c0 + c4 + j) * R + r0 + r4] = o;
    }
}

// ---------- MFMA GEMM (round-5 + XCD-chunked block swizzle) ----------
template <bool A_F32, bool OUT_F32>
__global__ __launch_bounds__(256, 2) void mfma_gemm_kernel(
    const void* __restrict__ A, int lda,
    const unsigned short* __restrict__ Wt,
    const float* __restrict__ bias,
    void* __restrict__ dst0, int sd0,
    void* __restrict__ dst1, int sd1, int ncut,
    int K)
{
    __shared__ unsigned short As[128 * 40];
    __shared__ unsigned short Bs[128 * 40];

    const int t    = threadIdx.x;
    // XCD-aware bijective swizzle (grids 960 / 320, both % 8 == 0).
    const int gx  = gridDim.x;
    const int nwg = gx * gridDim.y;
    int lin = blockIdx.y * gx + blockIdx.x;
    lin = (lin & 7) * (nwg >> 3) + (lin >> 3);
    const int m0   = (lin / gx) * 128;
    const int n0   = (lin % gx) * 128;
    const int lane = t & 63, wave = t >> 6;
    const int quad = lane >> 4, l15 = lane & 15;
    const int mw   = (wave >> 1) * 64;
    const int nw   = (wave & 1) * 64;
    const int r    = t >> 1;
    const int hh   = (t & 1) * 16;

    f32x4 acc[4][4];
#pragma unroll
    for (int i = 0; i < 4; ++i)
#pragma unroll
        for (int j = 0; j < 4; ++j) acc[i][j] = (f32x4){0.f, 0.f, 0.f, 0.f};

    const size_t a_base = (size_t)(m0 + r) * lda + hh;
    const unsigned short* bp = Wt + (size_t)(n0 + r) * K + hh;

    for (int k0 = 0; k0 < K; k0 += 32) {
        uint4 a0, a1;
        if (A_F32) {
            const float* ap = (const float*)A + a_base + k0;
            float4 f0 = *(const float4*)ap;
            float4 f1 = *(const float4*)(ap + 4);
            float4 f2 = *(const float4*)(ap + 8);
            float4 f3 = *(const float4*)(ap + 12);
            union { uint4 v; unsigned short s[8]; } u0, u1;
            u0.s[0]=f2bf(f0.x); u0.s[1]=f2bf(f0.y); u0.s[2]=f2bf(f0.z); u0.s[3]=f2bf(f0.w);
            u0.s[4]=f2bf(f1.x); u0.s[5]=f2bf(f1.y); u0.s[6]=f2bf(f1.z); u0.s[7]=f2bf(f1.w);
            u1.s[0]=f2bf(f2.x); u1.s[1]=f2bf(f2.y); u1.s[2]=f2bf(f2.z); u1.s[3]=f2bf(f2.w);
            u1.s[4]=f2bf(f3.x); u1.s[5]=f2bf(f3.y); u1.s[6]=f2bf(f3.z); u1.s[7]=f2bf(f3.w);
            a0 = u0.v; a1 = u1.v;
        } else {
            const unsigned short* ap = (const unsigned short*)A + a_base + k0;
            a0 = *(const uint4*)ap;
            a1 = *(const uint4*)(ap + 8);
        }
        uint4 b0 = *(const uint4*)(bp + k0);
        uint4 b1 = *(const uint4*)(bp + k0 + 8);
        __syncthreads();
        *(uint4*)&As[r * 40 + hh]     = a0;
        *(uint4*)&As[r * 40 + hh + 8] = a1;
        *(uint4*)&Bs[r * 40 + hh]     = b0;
        *(uint4*)&Bs[r * 40 + hh + 8] = b1;
        __syncthreads();

        bf16x8 af[4], bfr[4];
#pragma unroll
        for (int i = 0; i < 4; ++i)
            af[i] = *(const bf16x8*)&As[(mw + i * 16 + l15) * 40 + quad * 8];
#pragma unroll
        for (int j = 0; j < 4; ++j)
            bfr[j] = *(const bf16x8*)&Bs[(nw + j * 16 + l15) * 40 + quad * 8];
#pragma unroll
        for (int i = 0; i < 4; ++i)
#pragma unroll
            for (int j = 0; j < 4; ++j)
                acc[i][j] = __builtin_amdgcn_mfma_f32_16x16x32_bf16(af[i], bfr[j], acc[i][j], 0, 0, 0);
    }

#pragma unroll
    for (int j = 0; j < 4; ++j) {
        const int col = n0 + nw + j * 16 + l15;
        const float bv = bias[col];
        if (OUT_F32) {
            float* dst = (float*)dst0;
#pragma unroll
            for (int i = 0; i < 4; ++i) {
                const int rowb = m0 + mw + i * 16 + quad * 4;
#pragma unroll
                for (int g = 0; g < 4; ++g)
                    dst[(size_t)(rowb + g) * sd0 + col] = acc[i][j][g] + bv;
            }
        } else {
            unsigned short* dst; int sd, cc;
            if (col < ncut) { dst = (unsigned short*)dst0; sd = sd0; cc = col; }
            else            { dst = (unsigned short*)dst1; sd = sd1; cc = col - ncut; }
#pragma unroll
            for (int i = 0; i < 4; ++i) {
                const int rowb = m0 + mw + i * 16 + quad * 4;
#pragma unroll
                for (int g = 0; g < 4; ++g)
                    dst[(size_t)(rowb + g) * sd + cc] = f2bf(acc[i][j][g] + bv);
            }
        }
    }
}

// ---------- MFMA fused attention ----------
// Round-7: round-0 structure (NO register prefetch — it spilled at 4-block
// occupancy: WRITE_SIZE 10MB->662MB in round-6) plus the three verified-good
// deltas:
//   * __launch_bounds__(256,4): 4 blocks/CU resident (occupancy 26%->44%
//     measured). TLP hides staging latency instead of register prefetch.
//   * kg-inner V^T staging: LDS write banks cover all 32 (conflicts halved,
//     1.48e7 -> 7.7e6 measured).
//   * bijective XCD block swizzle for K/V L2 locality.
__global__ __launch_bounds__(256, 4) void attn_mfma_kernel(
    unsigned short* __restrict__ qk,         // [2048][5120] bf16: Q [0,2560), K [2560,5120)
    const unsigned short* __restrict__ vsrc, // [2048][2560] bf16 (parked in d_out)
    const float* __restrict__ gmats,
    const float* __restrict__ gphases,
    const float* __restrict__ gamps,
    const float* __restrict__ qphase,
    const float* __restrict__ is_ptr)
{
    __shared__ unsigned short Ks[64 * 104]; // Q tile (prologue) then K tiles; [row][d], pad d 80..96 = 0
    __shared__ unsigned short Vt[80 * 72];  // V^T [d][kj]
    __shared__ unsigned short Ps[64 * 72];  // P [q][kj] bf16
    __shared__ float cs[240];               // coeffs [3][80]

    const int t    = threadIdx.x;
    const int wave = t >> 6, lane = t & 63;
    const int quad = lane >> 4, l15 = lane & 15;
    // bijective XCD swizzle over 1024 blocks (8 XCDs x 128 chunks)
    const int lin0 = blockIdx.x;
    const int lin  = ((lin0 & 7) << 7) | (lin0 >> 3);
    const int qt = lin & 15;
    const int bh = lin >> 4;
    const int h  = bh & 31;
    const int b  = bh >> 5;

    const float scale = 0.111803398874989485f;   // 1/sqrt(80)
    const float c2    = scale * scale * is_ptr[0] * (1.0f / 3.0f);
    const float cosph = cosf(qphase[h]);

    if (t < 240) {
        int g = t / 80;
        float r0 = gmats[g*4+0] + gmats[g*4+1];
        float r1 = gmats[g*4+2] + gmats[g*4+3];
        cs[t] = (cosf(gphases[t]) * r0 + sinf(gphases[t]) * r1) * gamps[t];
    }

    const int srow = t >> 2;          // staging row 0..63 (wave w stages rows 16w..16w+15)
    const int scg  = (t & 3) * 20;    // staging col group (20 bf16)

    {   // stage Q tile into Ks + zero the d-pad [80,96)
        const unsigned short* qp = qk + (size_t)(b * S_ + qt * 64 + srow) * QK_ + h * D_ + scg;
#pragma unroll
        for (int u = 0; u < 5; ++u)
            *(ushort4*)&Ks[srow * 104 + scg + 4 * u] = *(const ushort4*)(qp + 4 * u);
        *(ushort4*)&Ks[srow * 104 + 80 + (t & 3) * 4] = (ushort4){0, 0, 0, 0};
    }
    __syncthreads();   // cs + Q visible

    // A-fragments: base Q + 3 coefficient-scaled variants (persist across k-tiles)
    bf16x8 afq[3], afg[3][3];
#pragma unroll
    for (int kc = 0; kc < 3; ++kc)
        afq[kc] = *(const bf16x8*)&Ks[(wave * 16 + l15) * 104 + quad * 8 + kc * 32];
#pragma unroll
    for (int g = 0; g < 3; ++g)
#pragma unroll
        for (int kc = 0; kc < 3; ++kc)
#pragma unroll
            for (int j = 0; j < 8; ++j) {
                int d = kc * 32 + quad * 8 + j;
                float c = (d < 80) ? cs[g * 80 + d] : 0.f;
                afg[g][kc][j] = (short)f2bf(bf2f((unsigned short)afq[kc][j]) * c);
            }

    f32x4 Ov[5];
#pragma unroll
    for (int nf = 0; nf < 5; ++nf) Ov[nf] = (f32x4){0.f, 0.f, 0.f, 0.f};
    float m_r[4] = {-INFINITY, -INFINITY, -INFINITY, -INFINITY};
    float l_r[4] = {0.f, 0.f, 0.f, 0.f};

    for (int kt = 0; kt < 16; ++kt) {
        __syncthreads();   // prev iter's Ks/Vt/Ps reads complete (iter0: Q-frag reads done)

        // ---- stage K tile [kj][d] into Ks (pad stays 0) ----
        const unsigned short* kp = qk + (size_t)(b * S_ + kt * 64 + srow) * QK_ + E_ + h * D_ + scg;
#pragma unroll
        for (int u = 0; u < 5; ++u)
            *(ushort4*)&Ks[srow * 104 + scg + 4 * u] = *(const ushort4*)(kp + 4 * u);

        // ---- stage V^T [d][kj] via 4x4 in-register transpose ----
        // kg-inner mapping: vkg = s&15, vdg = s>>4 -> LDS write banks
        // 16(vdg&1)+4j+2vkg cover all 32 exactly (conflict-free).
        for (int s = t; s < 320; s += 256) {
            const int vkg = s & 15, vdg = s >> 4;
            ushort4 rv[4];
#pragma unroll
            for (int i = 0; i < 4; ++i)
                rv[i] = *(const ushort4*)&vsrc[(size_t)(b * S_ + kt * 64 + vkg * 4 + i) * E_ + h * D_ + vdg * 4];
            const unsigned short rm[4][4] = {
                {rv[0].x, rv[0].y, rv[0].z, rv[0].w},
                {rv[1].x, rv[1].y, rv[1].z, rv[1].w},
                {rv[2].x, rv[2].y, rv[2].z, rv[2].w},
                {rv[3].x, rv[3].y, rv[3].z, rv[3].w}};
#pragma unroll
            for (int j = 0; j < 4; ++j) {
                ushort4 w = {rm[0][j], rm[1][j], rm[2][j], rm[3][j]};
                *(ushort4*)&Vt[(vdg * 4 + j) * 72 + vkg * 4] = w;
            }
        }
        __syncthreads();

        // ---- score MFMAs: 4 variants x 4 n-frags x 3 k-chunks ----
        f32x4 sacc[4][4];
#pragma unroll
        for (int v = 0; v < 4; ++v)
#pragma unroll
            for (int nf = 0; nf < 4; ++nf) sacc[v][nf] = (f32x4){0.f, 0.f, 0.f, 0.f};
#pragma unroll
        for (int kc = 0; kc < 3; ++kc) {
            bf16x8 bk[4];
#pragma unroll
            for (int nf = 0; nf < 4; ++nf)
                bk[nf] = *(const bf16x8*)&Ks[(nf * 16 + l15) * 104 + quad * 8 + kc * 32];
#pragma unroll
            for (int nf = 0; nf < 4; ++nf)
                sacc[0][nf] = __builtin_amdgcn_mfma_f32_16x16x32_bf16(afq[kc], bk[nf], sacc[0][nf], 0, 0, 0);
#pragma unroll
            for (int g = 0; g < 3; ++g)
#pragma unroll
                for (int nf = 0; nf < 4; ++nf)
                    sacc[1+g][nf] = __builtin_amdgcn_mfma_f32_16x16x32_bf16(afg[g][kc], bk[nf], sacc[1+g][nf], 0, 0, 0);
        }

        // ---- combine + online softmax (C layout: row=quad*4+r, col=l15+16nf) ----
        float p[4][4];   // [nf][r]
        float mx[4] = {-INFINITY, -INFINITY, -INFINITY, -INFINITY};
#pragma unroll
        for (int nf = 0; nf < 4; ++nf)
#pragma unroll
            for (int r = 0; r < 4; ++r) {
                float s0 = sacc[1][nf][r], s1 = sacc[2][nf][r], s2 = sacc[3][nf][r];
                float s = sacc[0][nf][r] * scale + (s0 * s1 + s0 * s2 + s1 * s2) * c2;
                p[nf][r] = s;
                mx[r] = fmaxf(mx[r], s);
            }
#pragma unroll
        for (int r = 0; r < 4; ++r) {
            mx[r] = fmaxf(mx[r], __shfl_xor(mx[r], 1));
            mx[r] = fmaxf(mx[r], __shfl_xor(mx[r], 2));
            mx[r] = fmaxf(mx[r], __shfl_xor(mx[r], 4));
            mx[r] = fmaxf(mx[r], __shfl_xor(mx[r], 8));
        }
        float alpha[4];
#pragma unroll
        for (int r = 0; r < 4; ++r) {
            float m_new = fmaxf(m_r[r], mx[r]);
            alpha[r] = __expf(m_r[r] - m_new);
            m_r[r] = m_new;
        }
#pragma unroll
        for (int nf = 0; nf < 4; ++nf)
#pragma unroll
            for (int r = 0; r < 4; ++r)
                p[nf][r] = __expf(p[nf][r] - m_r[r]);
#pragma unroll
        for (int r = 0; r < 4; ++r) {
            float s = p[0][r] + p[1][r] + p[2][r] + p[3][r];
            s += __shfl_xor(s, 1);
            s += __shfl_xor(s, 2);
            s += __shfl_xor(s, 4);
            s += __shfl_xor(s, 8);
            l_r[r] = l_r[r] * alpha[r] + s;
        }

        // ---- write P (bf16) to LDS; own-wave rows only ----
#pragma unroll
        for (int nf = 0; nf < 4; ++nf)
#pragma unroll
            for (int r = 0; r < 4; ++r)
                Ps[(wave * 16 + quad * 4 + r) * 72 + l15 + 16 * nf] = f2bf(p[nf][r]);
        __asm__ volatile("s_waitcnt lgkmcnt(0)" ::: "memory");

        // ---- O rescale + PV MFMAs ----
#pragma unroll
        for (int nf = 0; nf < 5; ++nf)
#pragma unroll
            for (int r = 0; r < 4; ++r) Ov[nf][r] *= alpha[r];

        bf16x8 ap[2];
#pragma unroll
        for (int kc = 0; kc < 2; ++kc)
            ap[kc] = *(const bf16x8*)&Ps[(wave * 16 + l15) * 72 + quad * 8 + kc * 32];
#pragma unroll
        for (int nf = 0; nf < 5; ++nf)
#pragma unroll
            for (int kc = 0; kc < 2; ++kc) {
                bf16x8 bv = *(const bf16x8*)&Vt[(nf * 16 + l15) * 72 + quad * 8 + kc * 32];
                Ov[nf] = __builtin_amdgcn_mfma_f32_16x16x32_bf16(ap[kc], bv, Ov[nf], 0, 0, 0);
            }
    }

    // ---- epilogue: O * cos(phase)/l -> Q section of qk (bf16) ----
    float inv[4];
#pragma unroll
    for (int r = 0; r < 4; ++r) inv[r] = cosph / l_r[r];
#pragma unroll
    for (int nf = 0; nf < 5; ++nf)
#pragma unroll
        for (int r = 0; r < 4; ++r)
            qk[(size_t)(b * S_ + qt * 64 + wave * 16 + quad * 4 + r) * QK_ + h * D_ + nf * 16 + l15]
                = f2bf(Ov[nf][r] * inv[r]);
}

extern "C" void kernel_launch(void* const* d_in, const int* in_sizes, int n_in,
                              void* d_out, int out_size, void* d_ws, size_t ws_size,
                              hipStream_t stream) {
    (void)in_sizes; (void)n_in; (void)out_size; (void)ws_size;
    const float* hidden  = (const float*)d_in[0];
    const float* Wqkv    = (const float*)d_in[1];
    const float* bqkv    = (const float*)d_in[2];
    const float* Wproj   = (const float*)d_in[3];
    const float* bproj   = (const float*)d_in[4];
    const float* gmats   = (const float*)d_in[5];
    const float* gphases = (const float*)d_in[6];
    const float* gamps   = (const float*)d_in[7];
    const float* qphase  = (const float*)d_in[8];
    const float* is_ptr  = (const float*)d_in[9];

    // ws layout (70.8 MB): qk_ws 21.0 MB | h_bf16 10.5 MB | Wt 39.3 MB (reused for Wproj_t)
    unsigned short* qk_ws  = (unsigned short*)d_ws;
    unsigned short* h_bf16 = (unsigned short*)((char*)d_ws + (size_t)M_ * QK_ * 2);
    unsigned short* Wt     = (unsigned short*)((char*)d_ws + (size_t)M_ * QK_ * 2 + (size_t)M_ * E_ * 2);
    unsigned short* v_buf  = (unsigned short*)d_out;   // V bf16 parked in d_out (consumed by attn)

    dim3 blk(256);
    cvt_bf16_kernel<<<dim3((M_ * E_ / 8 + 255) / 256), blk, 0, stream>>>(hidden, h_bf16, M_ * E_ / 8);
    transpose_bf16_kernel<<<dim3(E3_/64, E_/64), blk, 0, stream>>>(Wqkv, Wt, E_, E3_);
    mfma_gemm_kernel<false, false><<<dim3(E3_/128, M_/128), blk, 0, stream>>>(
        h_bf16, E_, Wt, bqkv, qk_ws, QK_, v_buf, E_, QK_, E_);
    attn_mfma_kernel<<<dim3(2 * H_ * (S_/64)), blk, 0, stream>>>(
        qk_ws, v_buf, gmats, gphases, gamps, qphase, is_ptr);
    transpose_bf16_kernel<<<dim3(E_/64, E_/64), blk, 0, stream>>>(Wproj, Wt, E_, E_);
    mfma_gemm_kernel<false, true><<<dim3(E_/128, M_/128), blk, 0, stream>>>(
        qk_ws, QK_, Wt, bproj, d_out, E_, d_out, E_, E_, E_);
}

// Round 3
// 508.761 us; speedup vs baseline: 1.4314x; 1.2652x over previous
//
#include <hip/hip_runtime.h>
#include <hip/hip_bf16.h>
#include <math.h>

#define S_  1024
#define E_  2560
#define H_  32
#define D_  80
#define E3_ 7680
#define M_  2048   // B*S
#define QK_ 5120   // packed Q|K row width in ws

typedef short bf16x8 __attribute__((ext_vector_type(8)));
typedef float f32x4  __attribute__((ext_vector_type(4)));

static __device__ __forceinline__ float bf2f(unsigned short u) {
    unsigned int i = ((unsigned int)u) << 16;
    float f; __builtin_memcpy(&f, &i, 4); return f;
}
static __device__ __forceinline__ unsigned short f2bf(float f) {
    unsigned int i; __builtin_memcpy(&i, &f, 4);
    i += 0x7fffu + ((i >> 16) & 1u);
    return (unsigned short)(i >> 16);
}

// ---------- pre-pass: fp32 -> bf16 flat convert ----------
__global__ __launch_bounds__(256) void cvt_bf16_kernel(
    const float* __restrict__ in, unsigned short* __restrict__ out, int n8)
{
    int i = (blockIdx.x * 256 + threadIdx.x);
    if (i >= n8) return;
    const float* p = in + (size_t)i * 8;
    float4 a = *(const float4*)p;
    float4 b = *(const float4*)(p + 4);
    union { uint4 v; unsigned short s[8]; } o;
    o.s[0]=f2bf(a.x); o.s[1]=f2bf(a.y); o.s[2]=f2bf(a.z); o.s[3]=f2bf(a.w);
    o.s[4]=f2bf(b.x); o.s[5]=f2bf(b.y); o.s[6]=f2bf(b.z); o.s[7]=f2bf(b.w);
    *(uint4*)(out + (size_t)i * 8) = o.v;
}

// ---------- pre-pass: fp32 [R][C] -> bf16 [C][R] transpose-convert ----------
__global__ __launch_bounds__(256) void transpose_bf16_kernel(
    const float* __restrict__ in, unsigned short* __restrict__ out, int R, int C)
{
    const int t = threadIdx.x;
    const int r0 = blockIdx.y * 64, c0 = blockIdx.x * 64;
    const int r4 = (t >> 4) * 4;
    const int c4 = (t & 15) * 4;
    float4 rows[4];
#pragma unroll
    for (int i = 0; i < 4; ++i)
        rows[i] = *(const float4*)&in[(size_t)(r0 + r4 + i) * C + c0 + c4];
    const float rv[4][4] = {
        {rows[0].x, rows[0].y, rows[0].z, rows[0].w},
        {rows[1].x, rows[1].y, rows[1].z, rows[1].w},
        {rows[2].x, rows[2].y, rows[2].z, rows[2].w},
        {rows[3].x, rows[3].y, rows[3].z, rows[3].w}};
#pragma unroll
    for (int j = 0; j < 4; ++j) {
        ushort4 o;
        o.x = f2bf(rv[0][j]); o.y = f2bf(rv[1][j]);
        o.z = f2bf(rv[2][j]); o.w = f2bf(rv[3][j]);
        *(ushort4*)&out[(size_t)(c0 + c4 + j) * R + r0 + r4] = o;
    }
}

// ---------- MFMA GEMM (round-5 + XCD-chunked block swizzle) ----------
template <bool A_F32, bool OUT_F32>
__global__ __launch_bounds__(256, 2) void mfma_gemm_kernel(
    const void* __restrict__ A, int lda,
    const unsigned short* __restrict__ Wt,
    const float* __restrict__ bias,
    void* __restrict__ dst0, int sd0,
    void* __restrict__ dst1, int sd1, int ncut,
    int K)
{
    __shared__ unsigned short As[128 * 40];
    __shared__ unsigned short Bs[128 * 40];

    const int t    = threadIdx.x;
    // XCD-aware bijective swizzle (grids 960 / 320, both % 8 == 0).
    const int gx  = gridDim.x;
    const int nwg = gx * gridDim.y;
    int lin = blockIdx.y * gx + blockIdx.x;
    lin = (lin & 7) * (nwg >> 3) + (lin >> 3);
    const int m0   = (lin / gx) * 128;
    const int n0   = (lin % gx) * 128;
    const int lane = t & 63, wave = t >> 6;
    const int quad = lane >> 4, l15 = lane & 15;
    const int mw   = (wave >> 1) * 64;
    const int nw   = (wave & 1) * 64;
    const int r    = t >> 1;
    const int hh   = (t & 1) * 16;

    f32x4 acc[4][4];
#pragma unroll
    for (int i = 0; i < 4; ++i)
#pragma unroll
        for (int j = 0; j < 4; ++j) acc[i][j] = (f32x4){0.f, 0.f, 0.f, 0.f};

    const size_t a_base = (size_t)(m0 + r) * lda + hh;
    const unsigned short* bp = Wt + (size_t)(n0 + r) * K + hh;

    for (int k0 = 0; k0 < K; k0 += 32) {
        uint4 a0, a1;
        if (A_F32) {
            const float* ap = (const float*)A + a_base + k0;
            float4 f0 = *(const float4*)ap;
            float4 f1 = *(const float4*)(ap + 4);
            float4 f2 = *(const float4*)(ap + 8);
            float4 f3 = *(const float4*)(ap + 12);
            union { uint4 v; unsigned short s[8]; } u0, u1;
            u0.s[0]=f2bf(f0.x); u0.s[1]=f2bf(f0.y); u0.s[2]=f2bf(f0.z); u0.s[3]=f2bf(f0.w);
            u0.s[4]=f2bf(f1.x); u0.s[5]=f2bf(f1.y); u0.s[6]=f2bf(f1.z); u0.s[7]=f2bf(f1.w);
            u1.s[0]=f2bf(f2.x); u1.s[1]=f2bf(f2.y); u1.s[2]=f2bf(f2.z); u1.s[3]=f2bf(f2.w);
            u1.s[4]=f2bf(f3.x); u1.s[5]=f2bf(f3.y); u1.s[6]=f2bf(f3.z); u1.s[7]=f2bf(f3.w);
            a0 = u0.v; a1 = u1.v;
        } else {
            const unsigned short* ap = (const unsigned short*)A + a_base + k0;
            a0 = *(const uint4*)ap;
            a1 = *(const uint4*)(ap + 8);
        }
        uint4 b0 = *(const uint4*)(bp + k0);
        uint4 b1 = *(const uint4*)(bp + k0 + 8);
        __syncthreads();
        *(uint4*)&As[r * 40 + hh]     = a0;
        *(uint4*)&As[r * 40 + hh + 8] = a1;
        *(uint4*)&Bs[r * 40 + hh]     = b0;
        *(uint4*)&Bs[r * 40 + hh + 8] = b1;
        __syncthreads();

        bf16x8 af[4], bfr[4];
#pragma unroll
        for (int i = 0; i < 4; ++i)
            af[i] = *(const bf16x8*)&As[(mw + i * 16 + l15) * 40 + quad * 8];
#pragma unroll
        for (int j = 0; j < 4; ++j)
            bfr[j] = *(const bf16x8*)&Bs[(nw + j * 16 + l15) * 40 + quad * 8];
#pragma unroll
        for (int i = 0; i < 4; ++i)
#pragma unroll
            for (int j = 0; j < 4; ++j)
                acc[i][j] = __builtin_amdgcn_mfma_f32_16x16x32_bf16(af[i], bfr[j], acc[i][j], 0, 0, 0);
    }

#pragma unroll
    for (int j = 0; j < 4; ++j) {
        const int col = n0 + nw + j * 16 + l15;
        const float bv = bias[col];
        if (OUT_F32) {
            float* dst = (float*)dst0;
#pragma unroll
            for (int i = 0; i < 4; ++i) {
                const int rowb = m0 + mw + i * 16 + quad * 4;
#pragma unroll
                for (int g = 0; g < 4; ++g)
                    dst[(size_t)(rowb + g) * sd0 + col] = acc[i][j][g] + bv;
            }
        } else {
            unsigned short* dst; int sd, cc;
            if (col < ncut) { dst = (unsigned short*)dst0; sd = sd0; cc = col; }
            else            { dst = (unsigned short*)dst1; sd = sd1; cc = col - ncut; }
#pragma unroll
            for (int i = 0; i < 4; ++i) {
                const int rowb = m0 + mw + i * 16 + quad * 4;
#pragma unroll
                for (int g = 0; g < 4; ++g)
                    dst[(size_t)(rowb + g) * sd + cc] = f2bf(acc[i][j][g] + bv);
            }
        }
    }
}

// ---------- MFMA fused attention ----------
// Round-8: register-pressure attack instead of launch-bounds forcing.
//   * __launch_bounds__(256,2): known-safe (round-0: VGPR 84, zero spill).
//     (256,3)/(256,4) both caused catastrophic scratch spills (WRITE_SIZE
//     10MB -> 398/662MB measured rounds 1-2).
//   * nf-split score loop: only sacc[4][2] (32 f32) live at once instead of
//     sacc[4][4] (64). Target: unified VGPR+AGPR alloc <= 170 so a 3rd
//     block/CU becomes resident organically (512/170 = 3 waves/SIMD).
//   * kg-inner V^T staging: conflict-free LDS write banks (verified:
//     conflicts 1.48e7 -> 7.75e6).
//   * bijective XCD block swizzle for K/V L2 locality.
__global__ __launch_bounds__(256, 2) void attn_mfma_kernel(
    unsigned short* __restrict__ qk,         // [2048][5120] bf16: Q [0,2560), K [2560,5120)
    const unsigned short* __restrict__ vsrc, // [2048][2560] bf16 (parked in d_out)
    const float* __restrict__ gmats,
    const float* __restrict__ gphases,
    const float* __restrict__ gamps,
    const float* __restrict__ qphase,
    const float* __restrict__ is_ptr)
{
    __shared__ unsigned short Ks[64 * 104]; // Q tile (prologue) then K tiles; [row][d], pad d 80..96 = 0
    __shared__ unsigned short Vt[80 * 72];  // V^T [d][kj]
    __shared__ unsigned short Ps[64 * 72];  // P [q][kj] bf16
    __shared__ float cs[240];               // coeffs [3][80]

    const int t    = threadIdx.x;
    const int wave = t >> 6, lane = t & 63;
    const int quad = lane >> 4, l15 = lane & 15;
    // bijective XCD swizzle over 1024 blocks (8 XCDs x 128 chunks)
    const int lin0 = blockIdx.x;
    const int lin  = ((lin0 & 7) << 7) | (lin0 >> 3);
    const int qt = lin & 15;
    const int bh = lin >> 4;
    const int h  = bh & 31;
    const int b  = bh >> 5;

    const float scale = 0.111803398874989485f;   // 1/sqrt(80)
    const float c2    = scale * scale * is_ptr[0] * (1.0f / 3.0f);
    const float cosph = cosf(qphase[h]);

    if (t < 240) {
        int g = t / 80;
        float r0 = gmats[g*4+0] + gmats[g*4+1];
        float r1 = gmats[g*4+2] + gmats[g*4+3];
        cs[t] = (cosf(gphases[t]) * r0 + sinf(gphases[t]) * r1) * gamps[t];
    }

    const int srow = t >> 2;          // staging row 0..63 (wave w stages rows 16w..16w+15)
    const int scg  = (t & 3) * 20;    // staging col group (20 bf16)

    {   // stage Q tile into Ks + zero the d-pad [80,96)
        const unsigned short* qp = qk + (size_t)(b * S_ + qt * 64 + srow) * QK_ + h * D_ + scg;
#pragma unroll
        for (int u = 0; u < 5; ++u)
            *(ushort4*)&Ks[srow * 104 + scg + 4 * u] = *(const ushort4*)(qp + 4 * u);
        *(ushort4*)&Ks[srow * 104 + 80 + (t & 3) * 4] = (ushort4){0, 0, 0, 0};
    }
    __syncthreads();   // cs + Q visible

    // A-fragments: base Q + 3 coefficient-scaled variants (persist across k-tiles)
    bf16x8 afq[3], afg[3][3];
#pragma unroll
    for (int kc = 0; kc < 3; ++kc)
        afq[kc] = *(const bf16x8*)&Ks[(wave * 16 + l15) * 104 + quad * 8 + kc * 32];
#pragma unroll
    for (int g = 0; g < 3; ++g)
#pragma unroll
        for (int kc = 0; kc < 3; ++kc)
#pragma unroll
            for (int j = 0; j < 8; ++j) {
                int d = kc * 32 + quad * 8 + j;
                float c = (d < 80) ? cs[g * 80 + d] : 0.f;
                afg[g][kc][j] = (short)f2bf(bf2f((unsigned short)afq[kc][j]) * c);
            }

    f32x4 Ov[5];
#pragma unroll
    for (int nf = 0; nf < 5; ++nf) Ov[nf] = (f32x4){0.f, 0.f, 0.f, 0.f};
    float m_r[4] = {-INFINITY, -INFINITY, -INFINITY, -INFINITY};
    float l_r[4] = {0.f, 0.f, 0.f, 0.f};

    for (int kt = 0; kt < 16; ++kt) {
        __syncthreads();   // prev iter's Ks/Vt/Ps reads complete (iter0: Q-frag reads done)

        // ---- stage K tile [kj][d] into Ks (pad stays 0) ----
        const unsigned short* kp = qk + (size_t)(b * S_ + kt * 64 + srow) * QK_ + E_ + h * D_ + scg;
#pragma unroll
        for (int u = 0; u < 5; ++u)
            *(ushort4*)&Ks[srow * 104 + scg + 4 * u] = *(const ushort4*)(kp + 4 * u);

        // ---- stage V^T [d][kj] via 4x4 in-register transpose ----
        // kg-inner mapping: vkg = s&15, vdg = s>>4 -> conflict-free LDS writes.
        for (int s = t; s < 320; s += 256) {
            const int vkg = s & 15, vdg = s >> 4;
            ushort4 rv[4];
#pragma unroll
            for (int i = 0; i < 4; ++i)
                rv[i] = *(const ushort4*)&vsrc[(size_t)(b * S_ + kt * 64 + vkg * 4 + i) * E_ + h * D_ + vdg * 4];
            const unsigned short rm[4][4] = {
                {rv[0].x, rv[0].y, rv[0].z, rv[0].w},
                {rv[1].x, rv[1].y, rv[1].z, rv[1].w},
                {rv[2].x, rv[2].y, rv[2].z, rv[2].w},
                {rv[3].x, rv[3].y, rv[3].z, rv[3].w}};
#pragma unroll
            for (int j = 0; j < 4; ++j) {
                ushort4 w = {rm[0][j], rm[1][j], rm[2][j], rm[3][j]};
                *(ushort4*)&Vt[(vdg * 4 + j) * 72 + vkg * 4] = w;
            }
        }
        __syncthreads();

        // ---- score MFMAs in two nf-halves: only sacc[4][2] live at once ----
        float p[4][4];   // [nf][r]
        float mx[4] = {-INFINITY, -INFINITY, -INFINITY, -INFINITY};
#pragma unroll
        for (int hf = 0; hf < 2; ++hf) {
            f32x4 sacc[4][2];
#pragma unroll
            for (int v = 0; v < 4; ++v)
#pragma unroll
                for (int n = 0; n < 2; ++n) sacc[v][n] = (f32x4){0.f, 0.f, 0.f, 0.f};
#pragma unroll
            for (int kc = 0; kc < 3; ++kc) {
                bf16x8 bk[2];
#pragma unroll
                for (int n = 0; n < 2; ++n)
                    bk[n] = *(const bf16x8*)&Ks[((hf * 2 + n) * 16 + l15) * 104 + quad * 8 + kc * 32];
#pragma unroll
                for (int n = 0; n < 2; ++n)
                    sacc[0][n] = __builtin_amdgcn_mfma_f32_16x16x32_bf16(afq[kc], bk[n], sacc[0][n], 0, 0, 0);
#pragma unroll
                for (int g = 0; g < 3; ++g)
#pragma unroll
                    for (int n = 0; n < 2; ++n)
                        sacc[1+g][n] = __builtin_amdgcn_mfma_f32_16x16x32_bf16(afg[g][kc], bk[n], sacc[1+g][n], 0, 0, 0);
            }
#pragma unroll
            for (int n = 0; n < 2; ++n)
#pragma unroll
                for (int r = 0; r < 4; ++r) {
                    float s0 = sacc[1][n][r], s1 = sacc[2][n][r], s2 = sacc[3][n][r];
                    float s = fmaf(fmaf(s0, s1, (s0 + s1) * s2), c2, sacc[0][n][r] * scale);
                    p[hf * 2 + n][r] = s;
                    mx[r] = fmaxf(mx[r], s);
                }
        }

        // ---- online softmax (C layout: row=quad*4+r, col=l15+16nf) ----
#pragma unroll
        for (int r = 0; r < 4; ++r) {
            mx[r] = fmaxf(mx[r], __shfl_xor(mx[r], 1));
            mx[r] = fmaxf(mx[r], __shfl_xor(mx[r], 2));
            mx[r] = fmaxf(mx[r], __shfl_xor(mx[r], 4));
            mx[r] = fmaxf(mx[r], __shfl_xor(mx[r], 8));
        }
        float alpha[4];
#pragma unroll
        for (int r = 0; r < 4; ++r) {
            float m_new = fmaxf(m_r[r], mx[r]);
            alpha[r] = __expf(m_r[r] - m_new);
            m_r[r] = m_new;
        }
#pragma unroll
        for (int nf = 0; nf < 4; ++nf)
#pragma unroll
            for (int r = 0; r < 4; ++r)
                p[nf][r] = __expf(p[nf][r] - m_r[r]);
#pragma unroll
        for (int r = 0; r < 4; ++r) {
            float s = p[0][r] + p[1][r] + p[2][r] + p[3][r];
            s += __shfl_xor(s, 1);
            s += __shfl_xor(s, 2);
            s += __shfl_xor(s, 4);
            s += __shfl_xor(s, 8);
            l_r[r] = l_r[r] * alpha[r] + s;
        }

        // ---- write P (bf16) to LDS; own-wave rows only ----
#pragma unroll
        for (int nf = 0; nf < 4; ++nf)
#pragma unroll
            for (int r = 0; r < 4; ++r)
                Ps[(wave * 16 + quad * 4 + r) * 72 + l15 + 16 * nf] = f2bf(p[nf][r]);
        __asm__ volatile("s_waitcnt lgkmcnt(0)" ::: "memory");

        // ---- O rescale + PV MFMAs ----
#pragma unroll
        for (int nf = 0; nf < 5; ++nf)
#pragma unroll
            for (int r = 0; r < 4; ++r) Ov[nf][r] *= alpha[r];

        bf16x8 ap[2];
#pragma unroll
        for (int kc = 0; kc < 2; ++kc)
            ap[kc] = *(const bf16x8*)&Ps[(wave * 16 + l15) * 72 + quad * 8 + kc * 32];
#pragma unroll
        for (int nf = 0; nf < 5; ++nf)
#pragma unroll
            for (int kc = 0; kc < 2; ++kc) {
                bf16x8 bv = *(const bf16x8*)&Vt[(nf * 16 + l15) * 72 + quad * 8 + kc * 32];
                Ov[nf] = __builtin_amdgcn_mfma_f32_16x16x32_bf16(ap[kc], bv, Ov[nf], 0, 0, 0);
            }
    }

    // ---- epilogue: O * cos(phase)/l -> Q section of qk (bf16) ----
    float inv[4];
#pragma unroll
    for (int r = 0; r < 4; ++r) inv[r] = cosph / l_r[r];
#pragma unroll
    for (int nf = 0; nf < 5; ++nf)
#pragma unroll
        for (int r = 0; r < 4; ++r)
            qk[(size_t)(b * S_ + qt * 64 + wave * 16 + quad * 4 + r) * QK_ + h * D_ + nf * 16 + l15]
                = f2bf(Ov[nf][r] * inv[r]);
}

extern "C" void kernel_launch(void* const* d_in, const int* in_sizes, int n_in,
                              void* d_out, int out_size, void* d_ws, size_t ws_size,
                              hipStream_t stream) {
    (void)in_sizes; (void)n_in; (void)out_size; (void)ws_size;
    const float* hidden  = (const float*)d_in[0];
    const float* Wqkv    = (const float*)d_in[1];
    const float* bqkv    = (const float*)d_in[2];
    const float* Wproj   = (const float*)d_in[3];
    const float* bproj   = (const float*)d_in[4];
    const float* gmats   = (const float*)d_in[5];
    const float* gphases = (const float*)d_in[6];
    const float* gamps   = (const float*)d_in[7];
    const float* qphase  = (const float*)d_in[8];
    const float* is_ptr  = (const float*)d_in[9];

    // ws layout (70.8 MB): qk_ws 21.0 MB | h_bf16 10.5 MB | Wt 39.3 MB (reused for Wproj_t)
    unsigned short* qk_ws  = (unsigned short*)d_ws;
    unsigned short* h_bf16 = (unsigned short*)((char*)d_ws + (size_t)M_ * QK_ * 2);
    unsigned short* Wt     = (unsigned short*)((char*)d_ws + (size_t)M_ * QK_ * 2 + (size_t)M_ * E_ * 2);
    unsigned short* v_buf  = (unsigned short*)d_out;   // V bf16 parked in d_out (consumed by attn)

    dim3 blk(256);
    cvt_bf16_kernel<<<dim3((M_ * E_ / 8 + 255) / 256), blk, 0, stream>>>(hidden, h_bf16, M_ * E_ / 8);
    transpose_bf16_kernel<<<dim3(E3_/64, E_/64), blk, 0, stream>>>(Wqkv, Wt, E_, E3_);
    mfma_gemm_kernel<false, false><<<dim3(E3_/128, M_/128), blk, 0, stream>>>(
        h_bf16, E_, Wt, bqkv, qk_ws, QK_, v_buf, E_, QK_, E_);
    attn_mfma_kernel<<<dim3(2 * H_ * (S_/64)), blk, 0, stream>>>(
        qk_ws, v_buf, gmats, gphases, gamps, qphase, is_ptr);
    transpose_bf16_kernel<<<dim3(E_/64, E_/64), blk, 0, stream>>>(Wproj, Wt, E_, E_);
    mfma_gemm_kernel<false, true><<<dim3(E_/128, M_/128), blk, 0, stream>>>(
        qk_ws, QK_, Wt, bproj, d_out, E_, d_out, E_, E_, E_);
}

// Round 4
// 489.232 us; speedup vs baseline: 1.4885x; 1.0399x over previous
//
#include <hip/hip_runtime.h>
#include <hip/hip_bf16.h>
#include <math.h>

#define S_  1024
#define E_  2560
#define H_  32
#define D_  80
#define E3_ 7680
#define M_  2048   // B*S
#define QK_ 5120   // packed Q|K row width in ws

typedef short bf16x8 __attribute__((ext_vector_type(8)));
typedef float f32x4  __attribute__((ext_vector_type(4)));

static __device__ __forceinline__ float bf2f(unsigned short u) {
    unsigned int i = ((unsigned int)u) << 16;
    float f; __builtin_memcpy(&f, &i, 4); return f;
}
static __device__ __forceinline__ unsigned short f2bf(float f) {
    unsigned int i; __builtin_memcpy(&i, &f, 4);
    i += 0x7fffu + ((i >> 16) & 1u);
    return (unsigned short)(i >> 16);
}

// async global->LDS 16B: dest = wave-uniform base + lane*16 (hardware rule)
static __device__ __forceinline__ void gload_lds16(
    const unsigned short* g, unsigned short* l)
{
    __builtin_amdgcn_global_load_lds(
        (const __attribute__((address_space(1))) void*)g,
        (__attribute__((address_space(3))) void*)l, 16, 0, 0);
}

// ---------- pre-pass: fp32 -> bf16 flat convert ----------
__global__ __launch_bounds__(256) void cvt_bf16_kernel(
    const float* __restrict__ in, unsigned short* __restrict__ out, int n8)
{
    int i = (blockIdx.x * 256 + threadIdx.x);
    if (i >= n8) return;
    const float* p = in + (size_t)i * 8;
    float4 a = *(const float4*)p;
    float4 b = *(const float4*)(p + 4);
    union { uint4 v; unsigned short s[8]; } o;
    o.s[0]=f2bf(a.x); o.s[1]=f2bf(a.y); o.s[2]=f2bf(a.z); o.s[3]=f2bf(a.w);
    o.s[4]=f2bf(b.x); o.s[5]=f2bf(b.y); o.s[6]=f2bf(b.z); o.s[7]=f2bf(b.w);
    *(uint4*)(out + (size_t)i * 8) = o.v;
}

// ---------- pre-pass: fp32 [R][C] -> bf16 [C][R] transpose-convert ----------
__global__ __launch_bounds__(256) void transpose_bf16_kernel(
    const float* __restrict__ in, unsigned short* __restrict__ out, int R, int C)
{
    const int t = threadIdx.x;
    const int r0 = blockIdx.y * 64, c0 = blockIdx.x * 64;
    const int r4 = (t >> 4) * 4;
    const int c4 = (t & 15) * 4;
    float4 rows[4];
#pragma unroll
    for (int i = 0; i < 4; ++i)
        rows[i] = *(const float4*)&in[(size_t)(r0 + r4 + i) * C + c0 + c4];
    const float rv[4][4] = {
        {rows[0].x, rows[0].y, rows[0].z, rows[0].w},
        {rows[1].x, rows[1].y, rows[1].z, rows[1].w},
        {rows[2].x, rows[2].y, rows[2].z, rows[2].w},
        {rows[3].x, rows[3].y, rows[3].z, rows[3].w}};
#pragma unroll
    for (int j = 0; j < 4; ++j) {
        ushort4 o;
        o.x = f2bf(rv[0][j]); o.y = f2bf(rv[1][j]);
        o.z = f2bf(rv[2][j]); o.w = f2bf(rv[3][j]);
        *(ushort4*)&out[(size_t)(c0 + c4 + j) * R + r0 + r4] = o;
    }
}

// ---------- MFMA GEMM, round-9: global_load_lds staging (m97 recipe) ----------
// Changes vs round-8:
//   * staging via __builtin_amdgcn_global_load_lds width-16: no VGPR round
//     trip, no ds_write, 4 async instrs/thread/K-step. (m193 isolated A/B:
//     +67% on this exact structure.)
//   * linear LDS [128][32] (8KB each), wave w stages rows [32w,32w+32).
//   * XCD swizzle REVERTED: B fits the 256MB LLC; measured round-3 QKV GEMM
//     157us vs <146us unswizzled round-0 (L3-fit => swizzle costs, m160).
//   * launch bounds relaxed to (256): VGPR ~112 unified -> 4 blocks/CU.
template <bool OUT_F32>
__global__ __launch_bounds__(256) void mfma_gemm_kernel(
    const unsigned short* __restrict__ A, int lda,
    const unsigned short* __restrict__ Wt,
    const float* __restrict__ bias,
    void* __restrict__ dst0, int sd0,
    void* __restrict__ dst1, int sd1, int ncut,
    int K)
{
    __shared__ unsigned short As[128 * 32];
    __shared__ unsigned short Bs[128 * 32];

    const int t    = threadIdx.x;
    const int m0   = blockIdx.y * 128;
    const int n0   = blockIdx.x * 128;
    const int lane = t & 63, wave = t >> 6;
    const int quad = lane >> 4, l15 = lane & 15;
    const int mw   = (wave >> 1) * 64;
    const int nw   = (wave & 1) * 64;

    f32x4 acc[4][4];
#pragma unroll
    for (int i = 0; i < 4; ++i)
#pragma unroll
        for (int j = 0; j < 4; ++j) acc[i][j] = (f32x4){0.f, 0.f, 0.f, 0.f};

    // staging geometry: lane l of wave w covers row (32w + 16c + l/4),
    // 16B slot (l&3); LDS dest = base + lane*16 (hardware-linear).
    const int srow  = lane >> 2;          // 0..15
    const int sslot = (lane & 3) * 8;     // shorts

    const unsigned short* gA0 = A  + (size_t)(m0 + wave * 32 + srow) * lda + sslot;
    const unsigned short* gA1 = gA0 + (size_t)16 * lda;
    const unsigned short* gB0 = Wt + (size_t)(n0 + wave * 32 + srow) * K + sslot;
    const unsigned short* gB1 = gB0 + (size_t)16 * K;
    unsigned short* lA0 = &As[(wave * 32) * 32];
    unsigned short* lA1 = &As[(wave * 32 + 16) * 32];
    unsigned short* lB0 = &Bs[(wave * 32) * 32];
    unsigned short* lB1 = &Bs[(wave * 32 + 16) * 32];

    for (int k0 = 0; k0 < K; k0 += 32) {
        __syncthreads();          // prior compute finished reading LDS
        gload_lds16(gA0 + k0, lA0);
        gload_lds16(gA1 + k0, lA1);
        gload_lds16(gB0 + k0, lB0);
        gload_lds16(gB1 + k0, lB1);
        __syncthreads();          // staging complete (vmcnt drained at barrier)

        bf16x8 af[4], bfr[4];
#pragma unroll
        for (int i = 0; i < 4; ++i)
            af[i] = *(const bf16x8*)&As[(mw + i * 16 + l15) * 32 + quad * 8];
#pragma unroll
        for (int j = 0; j < 4; ++j)
            bfr[j] = *(const bf16x8*)&Bs[(nw + j * 16 + l15) * 32 + quad * 8];
#pragma unroll
        for (int i = 0; i < 4; ++i)
#pragma unroll
            for (int j = 0; j < 4; ++j)
                acc[i][j] = __builtin_amdgcn_mfma_f32_16x16x32_bf16(af[i], bfr[j], acc[i][j], 0, 0, 0);
    }

#pragma unroll
    for (int j = 0; j < 4; ++j) {
        const int col = n0 + nw + j * 16 + l15;
        const float bv = bias[col];
        if (OUT_F32) {
            float* dst = (float*)dst0;
#pragma unroll
            for (int i = 0; i < 4; ++i) {
                const int rowb = m0 + mw + i * 16 + quad * 4;
#pragma unroll
                for (int g = 0; g < 4; ++g)
                    dst[(size_t)(rowb + g) * sd0 + col] = acc[i][j][g] + bv;
            }
        } else {
            unsigned short* dst; int sd, cc;
            if (col < ncut) { dst = (unsigned short*)dst0; sd = sd0; cc = col; }
            else            { dst = (unsigned short*)dst1; sd = sd1; cc = col - ncut; }
#pragma unroll
            for (int i = 0; i < 4; ++i) {
                const int rowb = m0 + mw + i * 16 + quad * 4;
#pragma unroll
                for (int g = 0; g < 4; ++g)
                    dst[(size_t)(rowb + g) * sd + cc] = f2bf(acc[i][j][g] + bv);
            }
        }
    }
}

// ---------- MFMA fused attention (round-8 version, unchanged) ----------
__global__ __launch_bounds__(256, 2) void attn_mfma_kernel(
    unsigned short* __restrict__ qk,         // [2048][5120] bf16: Q [0,2560), K [2560,5120)
    const unsigned short* __restrict__ vsrc, // [2048][2560] bf16 (parked in d_out)
    const float* __restrict__ gmats,
    const float* __restrict__ gphases,
    const float* __restrict__ gamps,
    const float* __restrict__ qphase,
    const float* __restrict__ is_ptr)
{
    __shared__ unsigned short Ks[64 * 104]; // Q tile (prologue) then K tiles; [row][d], pad d 80..96 = 0
    __shared__ unsigned short Vt[80 * 72];  // V^T [d][kj]
    __shared__ unsigned short Ps[64 * 72];  // P [q][kj] bf16
    __shared__ float cs[240];               // coeffs [3][80]

    const int t    = threadIdx.x;
    const int wave = t >> 6, lane = t & 63;
    const int quad = lane >> 4, l15 = lane & 15;
    // bijective XCD swizzle over 1024 blocks (8 XCDs x 128 chunks)
    const int lin0 = blockIdx.x;
    const int lin  = ((lin0 & 7) << 7) | (lin0 >> 3);
    const int qt = lin & 15;
    const int bh = lin >> 4;
    const int h  = bh & 31;
    const int b  = bh >> 5;

    const float scale = 0.111803398874989485f;   // 1/sqrt(80)
    const float c2    = scale * scale * is_ptr[0] * (1.0f / 3.0f);
    const float cosph = cosf(qphase[h]);

    if (t < 240) {
        int g = t / 80;
        float r0 = gmats[g*4+0] + gmats[g*4+1];
        float r1 = gmats[g*4+2] + gmats[g*4+3];
        cs[t] = (cosf(gphases[t]) * r0 + sinf(gphases[t]) * r1) * gamps[t];
    }

    const int srow = t >> 2;          // staging row 0..63 (wave w stages rows 16w..16w+15)
    const int scg  = (t & 3) * 20;    // staging col group (20 bf16)

    {   // stage Q tile into Ks + zero the d-pad [80,96)
        const unsigned short* qp = qk + (size_t)(b * S_ + qt * 64 + srow) * QK_ + h * D_ + scg;
#pragma unroll
        for (int u = 0; u < 5; ++u)
            *(ushort4*)&Ks[srow * 104 + scg + 4 * u] = *(const ushort4*)(qp + 4 * u);
        *(ushort4*)&Ks[srow * 104 + 80 + (t & 3) * 4] = (ushort4){0, 0, 0, 0};
    }
    __syncthreads();   // cs + Q visible

    // A-fragments: base Q + 3 coefficient-scaled variants (persist across k-tiles)
    bf16x8 afq[3], afg[3][3];
#pragma unroll
    for (int kc = 0; kc < 3; ++kc)
        afq[kc] = *(const bf16x8*)&Ks[(wave * 16 + l15) * 104 + quad * 8 + kc * 32];
#pragma unroll
    for (int g = 0; g < 3; ++g)
#pragma unroll
        for (int kc = 0; kc < 3; ++kc)
#pragma unroll
            for (int j = 0; j < 8; ++j) {
                int d = kc * 32 + quad * 8 + j;
                float c = (d < 80) ? cs[g * 80 + d] : 0.f;
                afg[g][kc][j] = (short)f2bf(bf2f((unsigned short)afq[kc][j]) * c);
            }

    f32x4 Ov[5];
#pragma unroll
    for (int nf = 0; nf < 5; ++nf) Ov[nf] = (f32x4){0.f, 0.f, 0.f, 0.f};
    float m_r[4] = {-INFINITY, -INFINITY, -INFINITY, -INFINITY};
    float l_r[4] = {0.f, 0.f, 0.f, 0.f};

    for (int kt = 0; kt < 16; ++kt) {
        __syncthreads();   // prev iter's Ks/Vt/Ps reads complete (iter0: Q-frag reads done)

        // ---- stage K tile [kj][d] into Ks (pad stays 0) ----
        const unsigned short* kp = qk + (size_t)(b * S_ + kt * 64 + srow) * QK_ + E_ + h * D_ + scg;
#pragma unroll
        for (int u = 0; u < 5; ++u)
            *(ushort4*)&Ks[srow * 104 + scg + 4 * u] = *(const ushort4*)(kp + 4 * u);

        // ---- stage V^T [d][kj] via 4x4 in-register transpose ----
        // kg-inner mapping: vkg = s&15, vdg = s>>4 -> conflict-free LDS writes.
        for (int s = t; s < 320; s += 256) {
            const int vkg = s & 15, vdg = s >> 4;
            ushort4 rv[4];
#pragma unroll
            for (int i = 0; i < 4; ++i)
                rv[i] = *(const ushort4*)&vsrc[(size_t)(b * S_ + kt * 64 + vkg * 4 + i) * E_ + h * D_ + vdg * 4];
            const unsigned short rm[4][4] = {
                {rv[0].x, rv[0].y, rv[0].z, rv[0].w},
                {rv[1].x, rv[1].y, rv[1].z, rv[1].w},
                {rv[2].x, rv[2].y, rv[2].z, rv[2].w},
                {rv[3].x, rv[3].y, rv[3].z, rv[3].w}};
#pragma unroll
            for (int j = 0; j < 4; ++j) {
                ushort4 w = {rm[0][j], rm[1][j], rm[2][j], rm[3][j]};
                *(ushort4*)&Vt[(vdg * 4 + j) * 72 + vkg * 4] = w;
            }
        }
        __syncthreads();

        // ---- score MFMAs in two nf-halves: only sacc[4][2] live at once ----
        float p[4][4];   // [nf][r]
        float mx[4] = {-INFINITY, -INFINITY, -INFINITY, -INFINITY};
#pragma unroll
        for (int hf = 0; hf < 2; ++hf) {
            f32x4 sacc[4][2];
#pragma unroll
            for (int v = 0; v < 4; ++v)
#pragma unroll
                for (int n = 0; n < 2; ++n) sacc[v][n] = (f32x4){0.f, 0.f, 0.f, 0.f};
#pragma unroll
            for (int kc = 0; kc < 3; ++kc) {
                bf16x8 bk[2];
#pragma unroll
                for (int n = 0; n < 2; ++n)
                    bk[n] = *(const bf16x8*)&Ks[((hf * 2 + n) * 16 + l15) * 104 + quad * 8 + kc * 32];
#pragma unroll
                for (int n = 0; n < 2; ++n)
                    sacc[0][n] = __builtin_amdgcn_mfma_f32_16x16x32_bf16(afq[kc], bk[n], sacc[0][n], 0, 0, 0);
#pragma unroll
                for (int g = 0; g < 3; ++g)
#pragma unroll
                    for (int n = 0; n < 2; ++n)
                        sacc[1+g][n] = __builtin_amdgcn_mfma_f32_16x16x32_bf16(afg[g][kc], bk[n], sacc[1+g][n], 0, 0, 0);
            }
#pragma unroll
            for (int n = 0; n < 2; ++n)
#pragma unroll
                for (int r = 0; r < 4; ++r) {
                    float s0 = sacc[1][n][r], s1 = sacc[2][n][r], s2 = sacc[3][n][r];
                    float s = fmaf(fmaf(s0, s1, (s0 + s1) * s2), c2, sacc[0][n][r] * scale);
                    p[hf * 2 + n][r] = s;
                    mx[r] = fmaxf(mx[r], s);
                }
        }

        // ---- online softmax (C layout: row=quad*4+r, col=l15+16nf) ----
#pragma unroll
        for (int r = 0; r < 4; ++r) {
            mx[r] = fmaxf(mx[r], __shfl_xor(mx[r], 1));
            mx[r] = fmaxf(mx[r], __shfl_xor(mx[r], 2));
            mx[r] = fmaxf(mx[r], __shfl_xor(mx[r], 4));
            mx[r] = fmaxf(mx[r], __shfl_xor(mx[r], 8));
        }
        float alpha[4];
#pragma unroll
        for (int r = 0; r < 4; ++r) {
            float m_new = fmaxf(m_r[r], mx[r]);
            alpha[r] = __expf(m_r[r] - m_new);
            m_r[r] = m_new;
        }
#pragma unroll
        for (int nf = 0; nf < 4; ++nf)
#pragma unroll
            for (int r = 0; r < 4; ++r)
                p[nf][r] = __expf(p[nf][r] - m_r[r]);
#pragma unroll
        for (int r = 0; r < 4; ++r) {
            float s = p[0][r] + p[1][r] + p[2][r] + p[3][r];
            s += __shfl_xor(s, 1);
            s += __shfl_xor(s, 2);
            s += __shfl_xor(s, 4);
            s += __shfl_xor(s, 8);
            l_r[r] = l_r[r] * alpha[r] + s;
        }

        // ---- write P (bf16) to LDS; own-wave rows only ----
#pragma unroll
        for (int nf = 0; nf < 4; ++nf)
#pragma unroll
            for (int r = 0; r < 4; ++r)
                Ps[(wave * 16 + quad * 4 + r) * 72 + l15 + 16 * nf] = f2bf(p[nf][r]);
        __asm__ volatile("s_waitcnt lgkmcnt(0)" ::: "memory");

        // ---- O rescale + PV MFMAs ----
#pragma unroll
        for (int nf = 0; nf < 5; ++nf)
#pragma unroll
            for (int r = 0; r < 4; ++r) Ov[nf][r] *= alpha[r];

        bf16x8 ap[2];
#pragma unroll
        for (int kc = 0; kc < 2; ++kc)
            ap[kc] = *(const bf16x8*)&Ps[(wave * 16 + l15) * 72 + quad * 8 + kc * 32];
#pragma unroll
        for (int nf = 0; nf < 5; ++nf)
#pragma unroll
            for (int kc = 0; kc < 2; ++kc) {
                bf16x8 bv = *(const bf16x8*)&Vt[(nf * 16 + l15) * 72 + quad * 8 + kc * 32];
                Ov[nf] = __builtin_amdgcn_mfma_f32_16x16x32_bf16(ap[kc], bv, Ov[nf], 0, 0, 0);
            }
    }

    // ---- epilogue: O * cos(phase)/l -> Q section of qk (bf16) ----
    float inv[4];
#pragma unroll
    for (int r = 0; r < 4; ++r) inv[r] = cosph / l_r[r];
#pragma unroll
    for (int nf = 0; nf < 5; ++nf)
#pragma unroll
        for (int r = 0; r < 4; ++r)
            qk[(size_t)(b * S_ + qt * 64 + wave * 16 + quad * 4 + r) * QK_ + h * D_ + nf * 16 + l15]
                = f2bf(Ov[nf][r] * inv[r]);
}

extern "C" void kernel_launch(void* const* d_in, const int* in_sizes, int n_in,
                              void* d_out, int out_size, void* d_ws, size_t ws_size,
                              hipStream_t stream) {
    (void)in_sizes; (void)n_in; (void)out_size; (void)ws_size;
    const float* hidden  = (const float*)d_in[0];
    const float* Wqkv    = (const float*)d_in[1];
    const float* bqkv    = (const float*)d_in[2];
    const float* Wproj   = (const float*)d_in[3];
    const float* bproj   = (const float*)d_in[4];
    const float* gmats   = (const float*)d_in[5];
    const float* gphases = (const float*)d_in[6];
    const float* gamps   = (const float*)d_in[7];
    const float* qphase  = (const float*)d_in[8];
    const float* is_ptr  = (const float*)d_in[9];

    // ws layout (70.8 MB): qk_ws 21.0 MB | h_bf16 10.5 MB | Wt 39.3 MB (reused for Wproj_t)
    unsigned short* qk_ws  = (unsigned short*)d_ws;
    unsigned short* h_bf16 = (unsigned short*)((char*)d_ws + (size_t)M_ * QK_ * 2);
    unsigned short* Wt     = (unsigned short*)((char*)d_ws + (size_t)M_ * QK_ * 2 + (size_t)M_ * E_ * 2);
    unsigned short* v_buf  = (unsigned short*)d_out;   // V bf16 parked in d_out (consumed by attn)

    dim3 blk(256);
    cvt_bf16_kernel<<<dim3((M_ * E_ / 8 + 255) / 256), blk, 0, stream>>>(hidden, h_bf16, M_ * E_ / 8);
    transpose_bf16_kernel<<<dim3(E3_/64, E_/64), blk, 0, stream>>>(Wqkv, Wt, E_, E3_);
    mfma_gemm_kernel<false><<<dim3(E3_/128, M_/128), blk, 0, stream>>>(
        h_bf16, E_, Wt, bqkv, qk_ws, QK_, v_buf, E_, QK_, E_);
    attn_mfma_kernel<<<dim3(2 * H_ * (S_/64)), blk, 0, stream>>>(
        qk_ws, v_buf, gmats, gphases, gamps, qphase, is_ptr);
    transpose_bf16_kernel<<<dim3(E_/64, E_/64), blk, 0, stream>>>(Wproj, Wt, E_, E_);
    mfma_gemm_kernel<true><<<dim3(E_/128, M_/128), blk, 0, stream>>>(
        qk_ws, QK_, Wt, bproj, d_out, E_, d_out, E_, E_, E_);
}

// Round 5
// 470.133 us; speedup vs baseline: 1.5490x; 1.0406x over previous
//
#include <hip/hip_runtime.h>
#include <hip/hip_bf16.h>
#include <math.h>

#define S_  1024
#define E_  2560
#define H_  32
#define D_  80
#define E3_ 7680
#define M_  2048   // B*S
#define QK_ 5120   // packed Q|K row width in ws

typedef short bf16x8 __attribute__((ext_vector_type(8)));
typedef float f32x4  __attribute__((ext_vector_type(4)));

static __device__ __forceinline__ float bf2f(unsigned short u) {
    unsigned int i = ((unsigned int)u) << 16;
    float f; __builtin_memcpy(&f, &i, 4); return f;
}
static __device__ __forceinline__ unsigned short f2bf(float f) {
    unsigned int i; __builtin_memcpy(&i, &f, 4);
    i += 0x7fffu + ((i >> 16) & 1u);
    return (unsigned short)(i >> 16);
}

// async global->LDS 16B: dest = wave-uniform base + lane*16 (hardware rule)
static __device__ __forceinline__ void gload_lds16(
    const unsigned short* g, unsigned short* l)
{
    __builtin_amdgcn_global_load_lds(
        (const __attribute__((address_space(1))) void*)g,
        (__attribute__((address_space(3))) void*)l, 16, 0, 0);
}

// ---------- pre-pass: fp32 -> bf16 flat convert ----------
__global__ __launch_bounds__(256) void cvt_bf16_kernel(
    const float* __restrict__ in, unsigned short* __restrict__ out, int n8)
{
    int i = (blockIdx.x * 256 + threadIdx.x);
    if (i >= n8) return;
    const float* p = in + (size_t)i * 8;
    float4 a = *(const float4*)p;
    float4 b = *(const float4*)(p + 4);
    union { uint4 v; unsigned short s[8]; } o;
    o.s[0]=f2bf(a.x); o.s[1]=f2bf(a.y); o.s[2]=f2bf(a.z); o.s[3]=f2bf(a.w);
    o.s[4]=f2bf(b.x); o.s[5]=f2bf(b.y); o.s[6]=f2bf(b.z); o.s[7]=f2bf(b.w);
    *(uint4*)(out + (size_t)i * 8) = o.v;
}

// ---------- pre-pass: fp32 [R][C] -> bf16 [C][R] transpose-convert ----------
__global__ __launch_bounds__(256) void transpose_bf16_kernel(
    const float* __restrict__ in, unsigned short* __restrict__ out, int R, int C)
{
    const int t = threadIdx.x;
    const int r0 = blockIdx.y * 64, c0 = blockIdx.x * 64;
    const int r4 = (t >> 4) * 4;
    const int c4 = (t & 15) * 4;
    float4 rows[4];
#pragma unroll
    for (int i = 0; i < 4; ++i)
        rows[i] = *(const float4*)&in[(size_t)(r0 + r4 + i) * C + c0 + c4];
    const float rv[4][4] = {
        {rows[0].x, rows[0].y, rows[0].z, rows[0].w},
        {rows[1].x, rows[1].y, rows[1].z, rows[1].w},
        {rows[2].x, rows[2].y, rows[2].z, rows[2].w},
        {rows[3].x, rows[3].y, rows[3].z, rows[3].w}};
#pragma unroll
    for (int j = 0; j < 4; ++j) {
        ushort4 o;
        o.x = f2bf(rv[0][j]); o.y = f2bf(rv[1][j]);
        o.z = f2bf(rv[2][j]); o.w = f2bf(rv[3][j]);
        *(ushort4*)&out[(size_t)(c0 + c4 + j) * R + r0 + r4] = o;
    }
}

// ---------- MFMA GEMM, round-10: T3-minimum 2-phase prefetch ----------
// Round-9 exposed the full staging latency each K-step:
//   barrier -> gload_lds -> barrier(vmcnt0 drain) -> compute  (556 TF, MfmaUtil 24%)
// Round-10 (T3-min recipe, m248v2): double-buffered LDS, stage NEXT K-step
// before computing current, ONE barrier per K-step. The compiler's
// vmcnt(0)-before-barrier drain now lands after the MFMAs, so HBM/L2 latency
// hides under compute.
template <bool OUT_F32>
__global__ __launch_bounds__(256) void mfma_gemm_kernel(
    const unsigned short* __restrict__ A, int lda,
    const unsigned short* __restrict__ Wt,
    const float* __restrict__ bias,
    void* __restrict__ dst0, int sd0,
    void* __restrict__ dst1, int sd1, int ncut,
    int K)
{
    __shared__ unsigned short As[2][128 * 32];
    __shared__ unsigned short Bs[2][128 * 32];
    const int BUFSZ = 128 * 32;

    const int t    = threadIdx.x;
    const int m0   = blockIdx.y * 128;
    const int n0   = blockIdx.x * 128;
    const int lane = t & 63, wave = t >> 6;
    const int quad = lane >> 4, l15 = lane & 15;
    const int mw   = (wave >> 1) * 64;
    const int nw   = (wave & 1) * 64;

    f32x4 acc[4][4];
#pragma unroll
    for (int i = 0; i < 4; ++i)
#pragma unroll
        for (int j = 0; j < 4; ++j) acc[i][j] = (f32x4){0.f, 0.f, 0.f, 0.f};

    // staging geometry: lane l of wave w covers row (32w + 16c + l/4),
    // 16B slot (l&3); LDS dest = wave-uniform base + lane*16 (hardware rule).
    const int srow  = lane >> 2;          // 0..15
    const int sslot = (lane & 3) * 8;     // shorts

    const unsigned short* gA0 = A  + (size_t)(m0 + wave * 32 + srow) * lda + sslot;
    const unsigned short* gA1 = gA0 + (size_t)16 * lda;
    const unsigned short* gB0 = Wt + (size_t)(n0 + wave * 32 + srow) * K + sslot;
    const unsigned short* gB1 = gB0 + (size_t)16 * K;
    unsigned short* lA0 = &As[0][(wave * 32) * 32];
    unsigned short* lA1 = lA0 + 16 * 32;
    unsigned short* lB0 = &Bs[0][(wave * 32) * 32];
    unsigned short* lB1 = lB0 + 16 * 32;

    // prologue: stage K-step 0 into buffer 0
    gload_lds16(gA0, lA0);
    gload_lds16(gA1, lA1);
    gload_lds16(gB0, lB0);
    gload_lds16(gB1, lB1);
    __syncthreads();   // vmcnt(0) drained by compiler before s_barrier

    int cur = 0;
    for (int k0 = 0; k0 < K; k0 += 32) {
        const int nxt = cur ^ 1;
        // issue next tile's async loads; they drain at the barrier AFTER compute
        if (k0 + 32 < K) {
            gload_lds16(gA0 + k0 + 32, lA0 + nxt * BUFSZ);
            gload_lds16(gA1 + k0 + 32, lA1 + nxt * BUFSZ);
            gload_lds16(gB0 + k0 + 32, lB0 + nxt * BUFSZ);
            gload_lds16(gB1 + k0 + 32, lB1 + nxt * BUFSZ);
        }

        const unsigned short* rA = &As[cur][0];
        const unsigned short* rB = &Bs[cur][0];
        bf16x8 af[4], bfr[4];
#pragma unroll
        for (int i = 0; i < 4; ++i)
            af[i] = *(const bf16x8*)&rA[(mw + i * 16 + l15) * 32 + quad * 8];
#pragma unroll
        for (int j = 0; j < 4; ++j)
            bfr[j] = *(const bf16x8*)&rB[(nw + j * 16 + l15) * 32 + quad * 8];
#pragma unroll
        for (int i = 0; i < 4; ++i)
#pragma unroll
            for (int j = 0; j < 4; ++j)
                acc[i][j] = __builtin_amdgcn_mfma_f32_16x16x32_bf16(af[i], bfr[j], acc[i][j], 0, 0, 0);

        __syncthreads();   // one barrier/K-step: reads of cur done + nxt staged
        cur = nxt;
    }

#pragma unroll
    for (int j = 0; j < 4; ++j) {
        const int col = n0 + nw + j * 16 + l15;
        const float bv = bias[col];
        if (OUT_F32) {
            float* dst = (float*)dst0;
#pragma unroll
            for (int i = 0; i < 4; ++i) {
                const int rowb = m0 + mw + i * 16 + quad * 4;
#pragma unroll
                for (int g = 0; g < 4; ++g)
                    dst[(size_t)(rowb + g) * sd0 + col] = acc[i][j][g] + bv;
            }
        } else {
            unsigned short* dst; int sd, cc;
            if (col < ncut) { dst = (unsigned short*)dst0; sd = sd0; cc = col; }
            else            { dst = (unsigned short*)dst1; sd = sd1; cc = col - ncut; }
#pragma unroll
            for (int i = 0; i < 4; ++i) {
                const int rowb = m0 + mw + i * 16 + quad * 4;
#pragma unroll
                for (int g = 0; g < 4; ++g)
                    dst[(size_t)(rowb + g) * sd + cc] = f2bf(acc[i][j][g] + bv);
            }
        }
    }
}

// ---------- MFMA fused attention (round-8 version, unchanged) ----------
__global__ __launch_bounds__(256, 2) void attn_mfma_kernel(
    unsigned short* __restrict__ qk,         // [2048][5120] bf16: Q [0,2560), K [2560,5120)
    const unsigned short* __restrict__ vsrc, // [2048][2560] bf16 (parked in d_out)
    const float* __restrict__ gmats,
    const float* __restrict__ gphases,
    const float* __restrict__ gamps,
    const float* __restrict__ qphase,
    const float* __restrict__ is_ptr)
{
    __shared__ unsigned short Ks[64 * 104]; // Q tile (prologue) then K tiles; [row][d], pad d 80..96 = 0
    __shared__ unsigned short Vt[80 * 72];  // V^T [d][kj]
    __shared__ unsigned short Ps[64 * 72];  // P [q][kj] bf16
    __shared__ float cs[240];               // coeffs [3][80]

    const int t    = threadIdx.x;
    const int wave = t >> 6, lane = t & 63;
    const int quad = lane >> 4, l15 = lane & 15;
    // bijective XCD swizzle over 1024 blocks (8 XCDs x 128 chunks)
    const int lin0 = blockIdx.x;
    const int lin  = ((lin0 & 7) << 7) | (lin0 >> 3);
    const int qt = lin & 15;
    const int bh = lin >> 4;
    const int h  = bh & 31;
    const int b  = bh >> 5;

    const float scale = 0.111803398874989485f;   // 1/sqrt(80)
    const float c2    = scale * scale * is_ptr[0] * (1.0f / 3.0f);
    const float cosph = cosf(qphase[h]);

    if (t < 240) {
        int g = t / 80;
        float r0 = gmats[g*4+0] + gmats[g*4+1];
        float r1 = gmats[g*4+2] + gmats[g*4+3];
        cs[t] = (cosf(gphases[t]) * r0 + sinf(gphases[t]) * r1) * gamps[t];
    }

    const int srow = t >> 2;          // staging row 0..63 (wave w stages rows 16w..16w+15)
    const int scg  = (t & 3) * 20;    // staging col group (20 bf16)

    {   // stage Q tile into Ks + zero the d-pad [80,96)
        const unsigned short* qp = qk + (size_t)(b * S_ + qt * 64 + srow) * QK_ + h * D_ + scg;
#pragma unroll
        for (int u = 0; u < 5; ++u)
            *(ushort4*)&Ks[srow * 104 + scg + 4 * u] = *(const ushort4*)(qp + 4 * u);
        *(ushort4*)&Ks[srow * 104 + 80 + (t & 3) * 4] = (ushort4){0, 0, 0, 0};
    }
    __syncthreads();   // cs + Q visible

    // A-fragments: base Q + 3 coefficient-scaled variants (persist across k-tiles)
    bf16x8 afq[3], afg[3][3];
#pragma unroll
    for (int kc = 0; kc < 3; ++kc)
        afq[kc] = *(const bf16x8*)&Ks[(wave * 16 + l15) * 104 + quad * 8 + kc * 32];
#pragma unroll
    for (int g = 0; g < 3; ++g)
#pragma unroll
        for (int kc = 0; kc < 3; ++kc)
#pragma unroll
            for (int j = 0; j < 8; ++j) {
                int d = kc * 32 + quad * 8 + j;
                float c = (d < 80) ? cs[g * 80 + d] : 0.f;
                afg[g][kc][j] = (short)f2bf(bf2f((unsigned short)afq[kc][j]) * c);
            }

    f32x4 Ov[5];
#pragma unroll
    for (int nf = 0; nf < 5; ++nf) Ov[nf] = (f32x4){0.f, 0.f, 0.f, 0.f};
    float m_r[4] = {-INFINITY, -INFINITY, -INFINITY, -INFINITY};
    float l_r[4] = {0.f, 0.f, 0.f, 0.f};

    for (int kt = 0; kt < 16; ++kt) {
        __syncthreads();   // prev iter's Ks/Vt/Ps reads complete (iter0: Q-frag reads done)

        // ---- stage K tile [kj][d] into Ks (pad stays 0) ----
        const unsigned short* kp = qk + (size_t)(b * S_ + kt * 64 + srow) * QK_ + E_ + h * D_ + scg;
#pragma unroll
        for (int u = 0; u < 5; ++u)
            *(ushort4*)&Ks[srow * 104 + scg + 4 * u] = *(const ushort4*)(kp + 4 * u);

        // ---- stage V^T [d][kj] via 4x4 in-register transpose ----
        // kg-inner mapping: vkg = s&15, vdg = s>>4 -> conflict-free LDS writes.
        for (int s = t; s < 320; s += 256) {
            const int vkg = s & 15, vdg = s >> 4;
            ushort4 rv[4];
#pragma unroll
            for (int i = 0; i < 4; ++i)
                rv[i] = *(const ushort4*)&vsrc[(size_t)(b * S_ + kt * 64 + vkg * 4 + i) * E_ + h * D_ + vdg * 4];
            const unsigned short rm[4][4] = {
                {rv[0].x, rv[0].y, rv[0].z, rv[0].w},
                {rv[1].x, rv[1].y, rv[1].z, rv[1].w},
                {rv[2].x, rv[2].y, rv[2].z, rv[2].w},
                {rv[3].x, rv[3].y, rv[3].z, rv[3].w}};
#pragma unroll
            for (int j = 0; j < 4; ++j) {
                ushort4 w = {rm[0][j], rm[1][j], rm[2][j], rm[3][j]};
                *(ushort4*)&Vt[(vdg * 4 + j) * 72 + vkg * 4] = w;
            }
        }
        __syncthreads();

        // ---- score MFMAs in two nf-halves: only sacc[4][2] live at once ----
        float p[4][4];   // [nf][r]
        float mx[4] = {-INFINITY, -INFINITY, -INFINITY, -INFINITY};
#pragma unroll
        for (int hf = 0; hf < 2; ++hf) {
            f32x4 sacc[4][2];
#pragma unroll
            for (int v = 0; v < 4; ++v)
#pragma unroll
                for (int n = 0; n < 2; ++n) sacc[v][n] = (f32x4){0.f, 0.f, 0.f, 0.f};
#pragma unroll
            for (int kc = 0; kc < 3; ++kc) {
                bf16x8 bk[2];
#pragma unroll
                for (int n = 0; n < 2; ++n)
                    bk[n] = *(const bf16x8*)&Ks[((hf * 2 + n) * 16 + l15) * 104 + quad * 8 + kc * 32];
#pragma unroll
                for (int n = 0; n < 2; ++n)
                    sacc[0][n] = __builtin_amdgcn_mfma_f32_16x16x32_bf16(afq[kc], bk[n], sacc[0][n], 0, 0, 0);
#pragma unroll
                for (int g = 0; g < 3; ++g)
#pragma unroll
                    for (int n = 0; n < 2; ++n)
                        sacc[1+g][n] = __builtin_amdgcn_mfma_f32_16x16x32_bf16(afg[g][kc], bk[n], sacc[1+g][n], 0, 0, 0);
            }
#pragma unroll
            for (int n = 0; n < 2; ++n)
#pragma unroll
                for (int r = 0; r < 4; ++r) {
                    float s0 = sacc[1][n][r], s1 = sacc[2][n][r], s2 = sacc[3][n][r];
                    float s = fmaf(fmaf(s0, s1, (s0 + s1) * s2), c2, sacc[0][n][r] * scale);
                    p[hf * 2 + n][r] = s;
                    mx[r] = fmaxf(mx[r], s);
                }
        }

        // ---- online softmax (C layout: row=quad*4+r, col=l15+16nf) ----
#pragma unroll
        for (int r = 0; r < 4; ++r) {
            mx[r] = fmaxf(mx[r], __shfl_xor(mx[r], 1));
            mx[r] = fmaxf(mx[r], __shfl_xor(mx[r], 2));
            mx[r] = fmaxf(mx[r], __shfl_xor(mx[r], 4));
            mx[r] = fmaxf(mx[r], __shfl_xor(mx[r], 8));
        }
        float alpha[4];
#pragma unroll
        for (int r = 0; r < 4; ++r) {
            float m_new = fmaxf(m_r[r], mx[r]);
            alpha[r] = __expf(m_r[r] - m_new);
            m_r[r] = m_new;
        }
#pragma unroll
        for (int nf = 0; nf < 4; ++nf)
#pragma unroll
            for (int r = 0; r < 4; ++r)
                p[nf][r] = __expf(p[nf][r] - m_r[r]);
#pragma unroll
        for (int r = 0; r < 4; ++r) {
            float s = p[0][r] + p[1][r] + p[2][r] + p[3][r];
            s += __shfl_xor(s, 1);
            s += __shfl_xor(s, 2);
            s += __shfl_xor(s, 4);
            s += __shfl_xor(s, 8);
            l_r[r] = l_r[r] * alpha[r] + s;
        }

        // ---- write P (bf16) to LDS; own-wave rows only ----
#pragma unroll
        for (int nf = 0; nf < 4; ++nf)
#pragma unroll
            for (int r = 0; r < 4; ++r)
                Ps[(wave * 16 + quad * 4 + r) * 72 + l15 + 16 * nf] = f2bf(p[nf][r]);
        __asm__ volatile("s_waitcnt lgkmcnt(0)" ::: "memory");

        // ---- O rescale + PV MFMAs ----
#pragma unroll
        for (int nf = 0; nf < 5; ++nf)
#pragma unroll
            for (int r = 0; r < 4; ++r) Ov[nf][r] *= alpha[r];

        bf16x8 ap[2];
#pragma unroll
        for (int kc = 0; kc < 2; ++kc)
            ap[kc] = *(const bf16x8*)&Ps[(wave * 16 + l15) * 72 + quad * 8 + kc * 32];
#pragma unroll
        for (int nf = 0; nf < 5; ++nf)
#pragma unroll
            for (int kc = 0; kc < 2; ++kc) {
                bf16x8 bv = *(const bf16x8*)&Vt[(nf * 16 + l15) * 72 + quad * 8 + kc * 32];
                Ov[nf] = __builtin_amdgcn_mfma_f32_16x16x32_bf16(ap[kc], bv, Ov[nf], 0, 0, 0);
            }
    }

    // ---- epilogue: O * cos(phase)/l -> Q section of qk (bf16) ----
    float inv[4];
#pragma unroll
    for (int r = 0; r < 4; ++r) inv[r] = cosph / l_r[r];
#pragma unroll
    for (int nf = 0; nf < 5; ++nf)
#pragma unroll
        for (int r = 0; r < 4; ++r)
            qk[(size_t)(b * S_ + qt * 64 + wave * 16 + quad * 4 + r) * QK_ + h * D_ + nf * 16 + l15]
                = f2bf(Ov[nf][r] * inv[r]);
}

extern "C" void kernel_launch(void* const* d_in, const int* in_sizes, int n_in,
                              void* d_out, int out_size, void* d_ws, size_t ws_size,
                              hipStream_t stream) {
    (void)in_sizes; (void)n_in; (void)out_size; (void)ws_size;
    const float* hidden  = (const float*)d_in[0];
    const float* Wqkv    = (const float*)d_in[1];
    const float* bqkv    = (const float*)d_in[2];
    const float* Wproj   = (const float*)d_in[3];
    const float* bproj   = (const float*)d_in[4];
    const float* gmats   = (const float*)d_in[5];
    const float* gphases = (const float*)d_in[6];
    const float* gamps   = (const float*)d_in[7];
    const float* qphase  = (const float*)d_in[8];
    const float* is_ptr  = (const float*)d_in[9];

    // ws layout (70.8 MB): qk_ws 21.0 MB | h_bf16 10.5 MB | Wt 39.3 MB (reused for Wproj_t)
    unsigned short* qk_ws  = (unsigned short*)d_ws;
    unsigned short* h_bf16 = (unsigned short*)((char*)d_ws + (size_t)M_ * QK_ * 2);
    unsigned short* Wt     = (unsigned short*)((char*)d_ws + (size_t)M_ * QK_ * 2 + (size_t)M_ * E_ * 2);
    unsigned short* v_buf  = (unsigned short*)d_out;   // V bf16 parked in d_out (consumed by attn)

    dim3 blk(256);
    cvt_bf16_kernel<<<dim3((M_ * E_ / 8 + 255) / 256), blk, 0, stream>>>(hidden, h_bf16, M_ * E_ / 8);
    transpose_bf16_kernel<<<dim3(E3_/64, E_/64), blk, 0, stream>>>(Wqkv, Wt, E_, E3_);
    mfma_gemm_kernel<false><<<dim3(E3_/128, M_/128), blk, 0, stream>>>(
        h_bf16, E_, Wt, bqkv, qk_ws, QK_, v_buf, E_, QK_, E_);
    attn_mfma_kernel<<<dim3(2 * H_ * (S_/64)), blk, 0, stream>>>(
        qk_ws, v_buf, gmats, gphases, gamps, qphase, is_ptr);
    transpose_bf16_kernel<<<dim3(E_/64, E_/64), blk, 0, stream>>>(Wproj, Wt, E_, E_);
    mfma_gemm_kernel<true><<<dim3(E_/128, M_/128), blk, 0, stream>>>(
        qk_ws, QK_, Wt, bproj, d_out, E_, d_out, E_, E_, E_);
}

// Round 6
// 455.639 us; speedup vs baseline: 1.5983x; 1.0318x over previous
//
#include <hip/hip_runtime.h>
#include <hip/hip_bf16.h>
#include <math.h>

#define S_  1024
#define E_  2560
#define H_  32
#define D_  80
#define E3_ 7680
#define M_  2048   // B*S
#define QK_ 5120   // packed Q|K row width in ws

typedef short bf16x8 __attribute__((ext_vector_type(8)));
typedef float f32x4  __attribute__((ext_vector_type(4)));

static __device__ __forceinline__ float bf2f(unsigned short u) {
    unsigned int i = ((unsigned int)u) << 16;
    float f; __builtin_memcpy(&f, &i, 4); return f;
}
static __device__ __forceinline__ unsigned short f2bf(float f) {
    unsigned int i; __builtin_memcpy(&i, &f, 4);
    i += 0x7fffu + ((i >> 16) & 1u);
    return (unsigned short)(i >> 16);
}

// async global->LDS 16B: dest = wave-uniform base + lane*16 (hardware rule)
static __device__ __forceinline__ void gload_lds16(
    const unsigned short* g, unsigned short* l)
{
    __builtin_amdgcn_global_load_lds(
        (const __attribute__((address_space(1))) void*)g,
        (__attribute__((address_space(3))) void*)l, 16, 0, 0);
}

// ---------- pre-pass: fp32 -> bf16 flat convert ----------
__global__ __launch_bounds__(256) void cvt_bf16_kernel(
    const float* __restrict__ in, unsigned short* __restrict__ out, int n8)
{
    int i = (blockIdx.x * 256 + threadIdx.x);
    if (i >= n8) return;
    const float* p = in + (size_t)i * 8;
    float4 a = *(const float4*)p;
    float4 b = *(const float4*)(p + 4);
    union { uint4 v; unsigned short s[8]; } o;
    o.s[0]=f2bf(a.x); o.s[1]=f2bf(a.y); o.s[2]=f2bf(a.z); o.s[3]=f2bf(a.w);
    o.s[4]=f2bf(b.x); o.s[5]=f2bf(b.y); o.s[6]=f2bf(b.z); o.s[7]=f2bf(b.w);
    *(uint4*)(out + (size_t)i * 8) = o.v;
}

// ---------- pre-pass: fp32 [R][C] -> bf16 [C][R] transpose-convert ----------
__global__ __launch_bounds__(256) void transpose_bf16_kernel(
    const float* __restrict__ in, unsigned short* __restrict__ out, int R, int C)
{
    const int t = threadIdx.x;
    const int r0 = blockIdx.y * 64, c0 = blockIdx.x * 64;
    const int r4 = (t >> 4) * 4;
    const int c4 = (t & 15) * 4;
    float4 rows[4];
#pragma unroll
    for (int i = 0; i < 4; ++i)
        rows[i] = *(const float4*)&in[(size_t)(r0 + r4 + i) * C + c0 + c4];
    const float rv[4][4] = {
        {rows[0].x, rows[0].y, rows[0].z, rows[0].w},
        {rows[1].x, rows[1].y, rows[1].z, rows[1].w},
        {rows[2].x, rows[2].y, rows[2].z, rows[2].w},
        {rows[3].x, rows[3].y, rows[3].z, rows[3].w}};
#pragma unroll
    for (int j = 0; j < 4; ++j) {
        ushort4 o;
        o.x = f2bf(rv[0][j]); o.y = f2bf(rv[1][j]);
        o.z = f2bf(rv[2][j]); o.w = f2bf(rv[3][j]);
        *(ushort4*)&out[(size_t)(c0 + c4 + j) * R + r0 + r4] = o;
    }
}

// ---------- MFMA GEMM (round-10: 2-phase gload_lds prefetch, unchanged) ----------
template <bool OUT_F32>
__global__ __launch_bounds__(256) void mfma_gemm_kernel(
    const unsigned short* __restrict__ A, int lda,
    const unsigned short* __restrict__ Wt,
    const float* __restrict__ bias,
    void* __restrict__ dst0, int sd0,
    void* __restrict__ dst1, int sd1, int ncut,
    int K)
{
    __shared__ unsigned short As[2][128 * 32];
    __shared__ unsigned short Bs[2][128 * 32];
    const int BUFSZ = 128 * 32;

    const int t    = threadIdx.x;
    const int m0   = blockIdx.y * 128;
    const int n0   = blockIdx.x * 128;
    const int lane = t & 63, wave = t >> 6;
    const int quad = lane >> 4, l15 = lane & 15;
    const int mw   = (wave >> 1) * 64;
    const int nw   = (wave & 1) * 64;

    f32x4 acc[4][4];
#pragma unroll
    for (int i = 0; i < 4; ++i)
#pragma unroll
        for (int j = 0; j < 4; ++j) acc[i][j] = (f32x4){0.f, 0.f, 0.f, 0.f};

    const int srow  = lane >> 2;          // 0..15
    const int sslot = (lane & 3) * 8;     // shorts

    const unsigned short* gA0 = A  + (size_t)(m0 + wave * 32 + srow) * lda + sslot;
    const unsigned short* gA1 = gA0 + (size_t)16 * lda;
    const unsigned short* gB0 = Wt + (size_t)(n0 + wave * 32 + srow) * K + sslot;
    const unsigned short* gB1 = gB0 + (size_t)16 * K;
    unsigned short* lA0 = &As[0][(wave * 32) * 32];
    unsigned short* lA1 = lA0 + 16 * 32;
    unsigned short* lB0 = &Bs[0][(wave * 32) * 32];
    unsigned short* lB1 = lB0 + 16 * 32;

    // prologue: stage K-step 0 into buffer 0
    gload_lds16(gA0, lA0);
    gload_lds16(gA1, lA1);
    gload_lds16(gB0, lB0);
    gload_lds16(gB1, lB1);
    __syncthreads();

    int cur = 0;
    for (int k0 = 0; k0 < K; k0 += 32) {
        const int nxt = cur ^ 1;
        if (k0 + 32 < K) {
            gload_lds16(gA0 + k0 + 32, lA0 + nxt * BUFSZ);
            gload_lds16(gA1 + k0 + 32, lA1 + nxt * BUFSZ);
            gload_lds16(gB0 + k0 + 32, lB0 + nxt * BUFSZ);
            gload_lds16(gB1 + k0 + 32, lB1 + nxt * BUFSZ);
        }

        const unsigned short* rA = &As[cur][0];
        const unsigned short* rB = &Bs[cur][0];
        bf16x8 af[4], bfr[4];
#pragma unroll
        for (int i = 0; i < 4; ++i)
            af[i] = *(const bf16x8*)&rA[(mw + i * 16 + l15) * 32 + quad * 8];
#pragma unroll
        for (int j = 0; j < 4; ++j)
            bfr[j] = *(const bf16x8*)&rB[(nw + j * 16 + l15) * 32 + quad * 8];
#pragma unroll
        for (int i = 0; i < 4; ++i)
#pragma unroll
            for (int j = 0; j < 4; ++j)
                acc[i][j] = __builtin_amdgcn_mfma_f32_16x16x32_bf16(af[i], bfr[j], acc[i][j], 0, 0, 0);

        __syncthreads();   // one barrier/K-step: reads of cur done + nxt staged
        cur = nxt;
    }

#pragma unroll
    for (int j = 0; j < 4; ++j) {
        const int col = n0 + nw + j * 16 + l15;
        const float bv = bias[col];
        if (OUT_F32) {
            float* dst = (float*)dst0;
#pragma unroll
            for (int i = 0; i < 4; ++i) {
                const int rowb = m0 + mw + i * 16 + quad * 4;
#pragma unroll
                for (int g = 0; g < 4; ++g)
                    dst[(size_t)(rowb + g) * sd0 + col] = acc[i][j][g] + bv;
            }
        } else {
            unsigned short* dst; int sd, cc;
            if (col < ncut) { dst = (unsigned short*)dst0; sd = sd0; cc = col; }
            else            { dst = (unsigned short*)dst1; sd = sd1; cc = col - ncut; }
#pragma unroll
            for (int i = 0; i < 4; ++i) {
                const int rowb = m0 + mw + i * 16 + quad * 4;
#pragma unroll
                for (int g = 0; g < 4; ++g)
                    dst[(size_t)(rowb + g) * sd + cc] = f2bf(acc[i][j][g] + bv);
            }
        }
    }
}

// ---------- MFMA fused attention ----------
// Round-11: T14 register prefetch of next K/V tile at (256,2).
// Round-1 proved the prefetch structure; it failed ONLY because (256,4)
// capped arch VGPRs at 64 and spilled. At 2 blocks/CU the per-wave unified
// budget is 256; usage ~132 + 26 prefetch regs fits with huge margin.
// Loads for tile t+1 issue right after tile t's staging barrier; their
// vmcnt wait lands under the ~3k cycles of score MFMA + softmax.
__global__ __launch_bounds__(256, 2) void attn_mfma_kernel(
    unsigned short* __restrict__ qk,         // [2048][5120] bf16: Q [0,2560), K [2560,5120)
    const unsigned short* __restrict__ vsrc, // [2048][2560] bf16 (parked in d_out)
    const float* __restrict__ gmats,
    const float* __restrict__ gphases,
    const float* __restrict__ gamps,
    const float* __restrict__ qphase,
    const float* __restrict__ is_ptr)
{
    __shared__ unsigned short Ks[64 * 104]; // Q tile (prologue) then K tiles; [row][d], pad d 80..96 = 0
    __shared__ unsigned short Vt[80 * 72];  // V^T [d][kj]
    __shared__ unsigned short Ps[64 * 72];  // P [q][kj] bf16
    __shared__ float cs[240];               // coeffs [3][80]

    const int t    = threadIdx.x;
    const int wave = t >> 6, lane = t & 63;
    const int quad = lane >> 4, l15 = lane & 15;
    // bijective XCD swizzle over 1024 blocks (8 XCDs x 128 chunks)
    const int lin0 = blockIdx.x;
    const int lin  = ((lin0 & 7) << 7) | (lin0 >> 3);
    const int qt = lin & 15;
    const int bh = lin >> 4;
    const int h  = bh & 31;
    const int b  = bh >> 5;

    const float scale = 0.111803398874989485f;   // 1/sqrt(80)
    const float c2    = scale * scale * is_ptr[0] * (1.0f / 3.0f);
    const float cosph = cosf(qphase[h]);

    if (t < 240) {
        int g = t / 80;
        float r0 = gmats[g*4+0] + gmats[g*4+1];
        float r1 = gmats[g*4+2] + gmats[g*4+3];
        cs[t] = (cosf(gphases[t]) * r0 + sinf(gphases[t]) * r1) * gamps[t];
    }

    const int srow = t >> 2;          // staging row 0..63 (wave w stages rows 16w..16w+15)
    const int scg  = (t & 3) * 20;    // staging col group (20 bf16)

    // V staging mapping (kg-inner, conflict-reduced):
    // item A (all t): kj-group vkg = t&15, d-group t>>4 (0..15)
    // item B (t<64):  kj-group vkg = t&15, d-group 16+(t>>4) (16..19)
    const int vkg  = t & 15;
    const int vdg0 = t >> 4;

    {   // stage Q tile into Ks + zero the d-pad [80,96)
        const unsigned short* qp = qk + (size_t)(b * S_ + qt * 64 + srow) * QK_ + h * D_ + scg;
#pragma unroll
        for (int u = 0; u < 5; ++u)
            *(ushort4*)&Ks[srow * 104 + scg + 4 * u] = *(const ushort4*)(qp + 4 * u);
        *(ushort4*)&Ks[srow * 104 + 80 + (t & 3) * 4] = (ushort4){0, 0, 0, 0};
    }
    __syncthreads();   // cs + Q visible

    // ---- prefetch tile 0 into registers (overlaps afq/afg build) ----
    ushort4 kpre[5];
    ushort4 vpre[8];
    {
        const unsigned short* kp = qk + (size_t)(b * S_ + srow) * QK_ + E_ + h * D_ + scg;
#pragma unroll
        for (int u = 0; u < 5; ++u) kpre[u] = *(const ushort4*)(kp + 4 * u);
        const unsigned short* vb = vsrc + (size_t)(b * S_) * E_ + h * D_;
#pragma unroll
        for (int i = 0; i < 4; ++i)
            vpre[i] = *(const ushort4*)(vb + (size_t)(vkg * 4 + i) * E_ + vdg0 * 4);
        if (t < 64) {
#pragma unroll
            for (int i = 0; i < 4; ++i)
                vpre[4 + i] = *(const ushort4*)(vb + (size_t)(vkg * 4 + i) * E_ + 64 + vdg0 * 4);
        }
    }

    // A-fragments: base Q + 3 coefficient-scaled variants (persist across k-tiles)
    bf16x8 afq[3], afg[3][3];
#pragma unroll
    for (int kc = 0; kc < 3; ++kc)
        afq[kc] = *(const bf16x8*)&Ks[(wave * 16 + l15) * 104 + quad * 8 + kc * 32];
#pragma unroll
    for (int g = 0; g < 3; ++g)
#pragma unroll
        for (int kc = 0; kc < 3; ++kc)
#pragma unroll
            for (int j = 0; j < 8; ++j) {
                int d = kc * 32 + quad * 8 + j;
                float c = (d < 80) ? cs[g * 80 + d] : 0.f;
                afg[g][kc][j] = (short)f2bf(bf2f((unsigned short)afq[kc][j]) * c);
            }

    f32x4 Ov[5];
#pragma unroll
    for (int nf = 0; nf < 5; ++nf) Ov[nf] = (f32x4){0.f, 0.f, 0.f, 0.f};
    float m_r[4] = {-INFINITY, -INFINITY, -INFINITY, -INFINITY};
    float l_r[4] = {0.f, 0.f, 0.f, 0.f};

    for (int kt = 0; kt < 16; ++kt) {
        __syncthreads();   // prev iter's Ks/Vt/Ps reads complete (iter0: Q-frag reads done)

        // ---- write prefetched K tile [kj][d] into Ks (pad stays 0) ----
#pragma unroll
        for (int u = 0; u < 5; ++u)
            *(ushort4*)&Ks[srow * 104 + scg + 4 * u] = kpre[u];

        // ---- write prefetched V^T [d][kj] via 4x4 in-register transpose ----
        {
            const unsigned short rm[4][4] = {
                {vpre[0].x, vpre[0].y, vpre[0].z, vpre[0].w},
                {vpre[1].x, vpre[1].y, vpre[1].z, vpre[1].w},
                {vpre[2].x, vpre[2].y, vpre[2].z, vpre[2].w},
                {vpre[3].x, vpre[3].y, vpre[3].z, vpre[3].w}};
#pragma unroll
            for (int j = 0; j < 4; ++j) {
                ushort4 w = {rm[0][j], rm[1][j], rm[2][j], rm[3][j]};
                *(ushort4*)&Vt[(vdg0 * 4 + j) * 72 + vkg * 4] = w;
            }
        }
        if (t < 64) {
            const unsigned short rm[4][4] = {
                {vpre[4].x, vpre[4].y, vpre[4].z, vpre[4].w},
                {vpre[5].x, vpre[5].y, vpre[5].z, vpre[5].w},
                {vpre[6].x, vpre[6].y, vpre[6].z, vpre[6].w},
                {vpre[7].x, vpre[7].y, vpre[7].z, vpre[7].w}};
#pragma unroll
            for (int j = 0; j < 4; ++j) {
                ushort4 w = {rm[0][j], rm[1][j], rm[2][j], rm[3][j]};
                *(ushort4*)&Vt[(64 + vdg0 * 4 + j) * 72 + vkg * 4] = w;
            }
        }
        __syncthreads();

        // ---- issue next tile's global loads; latency hides under compute ----
        if (kt < 15) {
            const unsigned short* kp = qk + (size_t)(b * S_ + (kt + 1) * 64 + srow) * QK_ + E_ + h * D_ + scg;
#pragma unroll
            for (int u = 0; u < 5; ++u) kpre[u] = *(const ushort4*)(kp + 4 * u);
            const unsigned short* vb = vsrc + (size_t)(b * S_ + (kt + 1) * 64) * E_ + h * D_;
#pragma unroll
            for (int i = 0; i < 4; ++i)
                vpre[i] = *(const ushort4*)(vb + (size_t)(vkg * 4 + i) * E_ + vdg0 * 4);
            if (t < 64) {
#pragma unroll
                for (int i = 0; i < 4; ++i)
                    vpre[4 + i] = *(const ushort4*)(vb + (size_t)(vkg * 4 + i) * E_ + 64 + vdg0 * 4);
            }
        }

        // ---- score MFMAs in two nf-halves: only sacc[4][2] live at once ----
        float p[4][4];   // [nf][r]
        float mx[4] = {-INFINITY, -INFINITY, -INFINITY, -INFINITY};
#pragma unroll
        for (int hf = 0; hf < 2; ++hf) {
            f32x4 sacc[4][2];
#pragma unroll
            for (int v = 0; v < 4; ++v)
#pragma unroll
                for (int n = 0; n < 2; ++n) sacc[v][n] = (f32x4){0.f, 0.f, 0.f, 0.f};
#pragma unroll
            for (int kc = 0; kc < 3; ++kc) {
                bf16x8 bk[2];
#pragma unroll
                for (int n = 0; n < 2; ++n)
                    bk[n] = *(const bf16x8*)&Ks[((hf * 2 + n) * 16 + l15) * 104 + quad * 8 + kc * 32];
#pragma unroll
                for (int n = 0; n < 2; ++n)
                    sacc[0][n] = __builtin_amdgcn_mfma_f32_16x16x32_bf16(afq[kc], bk[n], sacc[0][n], 0, 0, 0);
#pragma unroll
                for (int g = 0; g < 3; ++g)
#pragma unroll
                    for (int n = 0; n < 2; ++n)
                        sacc[1+g][n] = __builtin_amdgcn_mfma_f32_16x16x32_bf16(afg[g][kc], bk[n], sacc[1+g][n], 0, 0, 0);
            }
#pragma unroll
            for (int n = 0; n < 2; ++n)
#pragma unroll
                for (int r = 0; r < 4; ++r) {
                    float s0 = sacc[1][n][r], s1 = sacc[2][n][r], s2 = sacc[3][n][r];
                    float s = fmaf(fmaf(s0, s1, (s0 + s1) * s2), c2, sacc[0][n][r] * scale);
                    p[hf * 2 + n][r] = s;
                    mx[r] = fmaxf(mx[r], s);
                }
        }

        // ---- online softmax (C layout: row=quad*4+r, col=l15+16nf) ----
#pragma unroll
        for (int r = 0; r < 4; ++r) {
            mx[r] = fmaxf(mx[r], __shfl_xor(mx[r], 1));
            mx[r] = fmaxf(mx[r], __shfl_xor(mx[r], 2));
            mx[r] = fmaxf(mx[r], __shfl_xor(mx[r], 4));
            mx[r] = fmaxf(mx[r], __shfl_xor(mx[r], 8));
        }
        float alpha[4];
#pragma unroll
        for (int r = 0; r < 4; ++r) {
            float m_new = fmaxf(m_r[r], mx[r]);
            alpha[r] = __expf(m_r[r] - m_new);
            m_r[r] = m_new;
        }
#pragma unroll
        for (int nf = 0; nf < 4; ++nf)
#pragma unroll
            for (int r = 0; r < 4; ++r)
                p[nf][r] = __expf(p[nf][r] - m_r[r]);
#pragma unroll
        for (int r = 0; r < 4; ++r) {
            float s = p[0][r] + p[1][r] + p[2][r] + p[3][r];
            s += __shfl_xor(s, 1);
            s += __shfl_xor(s, 2);
            s += __shfl_xor(s, 4);
            s += __shfl_xor(s, 8);
            l_r[r] = l_r[r] * alpha[r] + s;
        }

        // ---- write P (bf16) to LDS; own-wave rows only ----
#pragma unroll
        for (int nf = 0; nf < 4; ++nf)
#pragma unroll
            for (int r = 0; r < 4; ++r)
                Ps[(wave * 16 + quad * 4 + r) * 72 + l15 + 16 * nf] = f2bf(p[nf][r]);
        __asm__ volatile("s_waitcnt lgkmcnt(0)" ::: "memory");

        // ---- O rescale + PV MFMAs ----
#pragma unroll
        for (int nf = 0; nf < 5; ++nf)
#pragma unroll
            for (int r = 0; r < 4; ++r) Ov[nf][r] *= alpha[r];

        bf16x8 ap[2];
#pragma unroll
        for (int kc = 0; kc < 2; ++kc)
            ap[kc] = *(const bf16x8*)&Ps[(wave * 16 + l15) * 72 + quad * 8 + kc * 32];
#pragma unroll
        for (int nf = 0; nf < 5; ++nf)
#pragma unroll
            for (int kc = 0; kc < 2; ++kc) {
                bf16x8 bv = *(const bf16x8*)&Vt[(nf * 16 + l15) * 72 + quad * 8 + kc * 32];
                Ov[nf] = __builtin_amdgcn_mfma_f32_16x16x32_bf16(ap[kc], bv, Ov[nf], 0, 0, 0);
            }
    }

    // ---- epilogue: O * cos(phase)/l -> Q section of qk (bf16) ----
    float inv[4];
#pragma unroll
    for (int r = 0; r < 4; ++r) inv[r] = cosph / l_r[r];
#pragma unroll
    for (int nf = 0; nf < 5; ++nf)
#pragma unroll
        for (int r = 0; r < 4; ++r)
            qk[(size_t)(b * S_ + qt * 64 + wave * 16 + quad * 4 + r) * QK_ + h * D_ + nf * 16 + l15]
                = f2bf(Ov[nf][r] * inv[r]);
}

extern "C" void kernel_launch(void* const* d_in, const int* in_sizes, int n_in,
                              void* d_out, int out_size, void* d_ws, size_t ws_size,
                              hipStream_t stream) {
    (void)in_sizes; (void)n_in; (void)out_size; (void)ws_size;
    const float* hidden  = (const float*)d_in[0];
    const float* Wqkv    = (const float*)d_in[1];
    const float* bqkv    = (const float*)d_in[2];
    const float* Wproj   = (const float*)d_in[3];
    const float* bproj   = (const float*)d_in[4];
    const float* gmats   = (const float*)d_in[5];
    const float* gphases = (const float*)d_in[6];
    const float* gamps   = (const float*)d_in[7];
    const float* qphase  = (const float*)d_in[8];
    const float* is_ptr  = (const float*)d_in[9];

    // ws layout (70.8 MB): qk_ws 21.0 MB | h_bf16 10.5 MB | Wt 39.3 MB (reused for Wproj_t)
    unsigned short* qk_ws  = (unsigned short*)d_ws;
    unsigned short* h_bf16 = (unsigned short*)((char*)d_ws + (size_t)M_ * QK_ * 2);
    unsigned short* Wt     = (unsigned short*)((char*)d_ws + (size_t)M_ * QK_ * 2 + (size_t)M_ * E_ * 2);
    unsigned short* v_buf  = (unsigned short*)d_out;   // V bf16 parked in d_out (consumed by attn)

    dim3 blk(256);
    cvt_bf16_kernel<<<dim3((M_ * E_ / 8 + 255) / 256), blk, 0, stream>>>(hidden, h_bf16, M_ * E_ / 8);
    transpose_bf16_kernel<<<dim3(E3_/64, E_/64), blk, 0, stream>>>(Wqkv, Wt, E_, E3_);
    mfma_gemm_kernel<false><<<dim3(E3_/128, M_/128), blk, 0, stream>>>(
        h_bf16, E_, Wt, bqkv, qk_ws, QK_, v_buf, E_, QK_, E_);
    attn_mfma_kernel<<<dim3(2 * H_ * (S_/64)), blk, 0, stream>>>(
        qk_ws, v_buf, gmats, gphases, gamps, qphase, is_ptr);
    transpose_bf16_kernel<<<dim3(E_/64, E_/64), blk, 0, stream>>>(Wproj, Wt, E_, E_);
    mfma_gemm_kernel<true><<<dim3(E_/128, M_/128), blk, 0, stream>>>(
        qk_ws, QK_, Wt, bproj, d_out, E_, d_out, E_, E_, E_);
}

// Round 7
// 418.338 us; speedup vs baseline: 1.7408x; 1.0892x over previous
//
#include <hip/hip_runtime.h>
#include <hip/hip_bf16.h>
#include <math.h>

#define S_  1024
#define E_  2560
#define H_  32
#define D_  80
#define E3_ 7680
#define M_  2048   // B*S
#define QK_ 5120   // packed Q|K row width in ws

typedef short bf16x8 __attribute__((ext_vector_type(8)));
typedef float f32x4  __attribute__((ext_vector_type(4)));

static __device__ __forceinline__ float bf2f(unsigned short u) {
    unsigned int i = ((unsigned int)u) << 16;
    float f; __builtin_memcpy(&f, &i, 4); return f;
}
static __device__ __forceinline__ unsigned short f2bf(float f) {
    unsigned int i; __builtin_memcpy(&i, &f, 4);
    i += 0x7fffu + ((i >> 16) & 1u);
    return (unsigned short)(i >> 16);
}

// async global->LDS 16B: dest = wave-uniform base + lane*16 (hardware rule)
static __device__ __forceinline__ void gload_lds16(
    const unsigned short* g, unsigned short* l)
{
    __builtin_amdgcn_global_load_lds(
        (const __attribute__((address_space(1))) void*)g,
        (__attribute__((address_space(3))) void*)l, 16, 0, 0);
}

// ---------- pre-pass: fp32 -> bf16 flat convert ----------
__global__ __launch_bounds__(256) void cvt_bf16_kernel(
    const float* __restrict__ in, unsigned short* __restrict__ out, int n8)
{
    int i = (blockIdx.x * 256 + threadIdx.x);
    if (i >= n8) return;
    const float* p = in + (size_t)i * 8;
    float4 a = *(const float4*)p;
    float4 b = *(const float4*)(p + 4);
    union { uint4 v; unsigned short s[8]; } o;
    o.s[0]=f2bf(a.x); o.s[1]=f2bf(a.y); o.s[2]=f2bf(a.z); o.s[3]=f2bf(a.w);
    o.s[4]=f2bf(b.x); o.s[5]=f2bf(b.y); o.s[6]=f2bf(b.z); o.s[7]=f2bf(b.w);
    *(uint4*)(out + (size_t)i * 8) = o.v;
}

// ---------- pre-pass: fp32 [R][C] -> bf16 [C][R] transpose-convert ----------
__global__ __launch_bounds__(256) void transpose_bf16_kernel(
    const float* __restrict__ in, unsigned short* __restrict__ out, int R, int C)
{
    const int t = threadIdx.x;
    const int r0 = blockIdx.y * 64, c0 = blockIdx.x * 64;
    const int r4 = (t >> 4) * 4;
    const int c4 = (t & 15) * 4;
    float4 rows[4];
#pragma unroll
    for (int i = 0; i < 4; ++i)
        rows[i] = *(const float4*)&in[(size_t)(r0 + r4 + i) * C + c0 + c4];
    const float rv[4][4] = {
        {rows[0].x, rows[0].y, rows[0].z, rows[0].w},
        {rows[1].x, rows[1].y, rows[1].z, rows[1].w},
        {rows[2].x, rows[2].y, rows[2].z, rows[2].w},
        {rows[3].x, rows[3].y, rows[3].z, rows[3].w}};
#pragma unroll
    for (int j = 0; j < 4; ++j) {
        ushort4 o;
        o.x = f2bf(rv[0][j]); o.y = f2bf(rv[1][j]);
        o.z = f2bf(rv[2][j]); o.w = f2bf(rv[3][j]);
        *(ushort4*)&out[(size_t)(c0 + c4 + j) * R + r0 + r4] = o;
    }
}

// ---------- MFMA GEMM 256x256xBK64, 8 waves (round-12, QKV) ----------
// Same proven schedule as round-10 (one __syncthreads per K-tile; stage-next
// issued right after the sync so its latency hides under this tile's 64 MFMAs
// ~2480 SIMD-cyc — 4x the window of the 128x32 structure), plus conflict-free
// LDS slot rotation:
//   physical_slot = (logical_slot + row) & 7 on [256][64] bf16 tiles.
//   gload_lds writes linearly; the per-lane GLOBAL source is inverse-rotated
//   (ls = ((lane&7) - (lane>>3)) & 7) so data lands pre-swizzled (rule #21);
//   ds_read applies the same rotation -> each 16-lane phase group covers all
//   8 bank-groups x2 = 2-way = free (was 16-way on linear 128B-stride rows).
__global__ __launch_bounds__(512, 2) void mfma_gemm256_kernel(
    const unsigned short* __restrict__ A, int lda,   // [M][K] bf16
    const unsigned short* __restrict__ Wt,           // [N][K] bf16
    const float* __restrict__ bias,
    unsigned short* __restrict__ dst0, int sd0,
    unsigned short* __restrict__ dst1, int sd1, int ncut,
    int K)
{
    // [buf][A=0/B=1][row*64 + slot*8 + e] : 2*2*16384 shorts = 128 KB
    __shared__ unsigned short lds[2][2][256 * 64];

    const int t    = threadIdx.x;
    const int lane = t & 63, wave = t >> 6;          // 8 waves
    const int quad = lane >> 4, l15 = lane & 15;
    const int wm   = wave >> 2, wn = wave & 3;       // 2 x 4 wave grid
    const int m0   = blockIdx.y * 256;
    const int n0   = blockIdx.x * 256;

    // staging: wave stages rows [32w, 32w+32) of the A-tile and B-tile.
    // instr i covers 8 rows (1KB). lane l: row offset pr=l>>3, logical slot
    // ls=((l&7)-pr)&7 (inverse rotation; rows stay 128B-coalesced).
    const int pr = lane >> 3;
    const int ls = ((lane & 7) - pr) & 7;
    const unsigned short* gA[4];
    const unsigned short* gB[4];
#pragma unroll
    for (int i = 0; i < 4; ++i) {
        const int r = wave * 32 + i * 8 + pr;
        gA[i] = A  + (size_t)(m0 + r) * lda + ls * 8;
        gB[i] = Wt + (size_t)(n0 + r) * K   + ls * 8;
    }

    f32x4 acc[8][4];
#pragma unroll
    for (int mf = 0; mf < 8; ++mf)
#pragma unroll
        for (int nf = 0; nf < 4; ++nf) acc[mf][nf] = (f32x4){0.f, 0.f, 0.f, 0.f};

    // prologue: stage tile 0 into buf 0
#pragma unroll
    for (int i = 0; i < 4; ++i) {
        gload_lds16(gA[i], &lds[0][0][(wave * 32 + i * 8) * 64]);
        gload_lds16(gB[i], &lds[0][1][(wave * 32 + i * 8) * 64]);
    }

    const int NT = K / 64;   // 40
    for (int kt = 0; kt < NT; ++kt) {
        __syncthreads();   // tile kt staged+drained; prev reads of other buf done

        if (kt + 1 < NT) {
            const int nb = (kt + 1) & 1;
            const size_t koff = (size_t)(kt + 1) * 64;
#pragma unroll
            for (int i = 0; i < 4; ++i) {
                gload_lds16(gA[i] + koff, &lds[nb][0][(wave * 32 + i * 8) * 64]);
                gload_lds16(gB[i] + koff, &lds[nb][1][(wave * 32 + i * 8) * 64]);
            }
        }

        const unsigned short* As = &lds[kt & 1][0][0];
        const unsigned short* Bs = &lds[kt & 1][1][0];
#pragma unroll
        for (int kc = 0; kc < 2; ++kc) {
            bf16x8 bfr[4];
#pragma unroll
            for (int nf = 0; nf < 4; ++nf) {
                const int row = wn * 64 + nf * 16 + l15;
                const int ps  = (quad + 4 * kc + (row & 7)) & 7;
                bfr[nf] = *(const bf16x8*)&Bs[row * 64 + ps * 8];
            }
#pragma unroll
            for (int mf = 0; mf < 8; ++mf) {
                const int row = wm * 128 + mf * 16 + l15;
                const int ps  = (quad + 4 * kc + (row & 7)) & 7;
                const bf16x8 af = *(const bf16x8*)&As[row * 64 + ps * 8];
#pragma unroll
                for (int nf = 0; nf < 4; ++nf)
                    acc[mf][nf] = __builtin_amdgcn_mfma_f32_16x16x32_bf16(af, bfr[nf], acc[mf][nf], 0, 0, 0);
            }
        }
    }

    // epilogue: bf16 store, split at ncut
#pragma unroll
    for (int nf = 0; nf < 4; ++nf) {
        const int col = n0 + wn * 64 + nf * 16 + l15;
        const float bv = bias[col];
        unsigned short* dst; int sd, cc;
        if (col < ncut) { dst = dst0; sd = sd0; cc = col; }
        else            { dst = dst1; sd = sd1; cc = col - ncut; }
#pragma unroll
        for (int mf = 0; mf < 8; ++mf) {
            const int rowb = m0 + wm * 128 + mf * 16 + quad * 4;
#pragma unroll
            for (int g = 0; g < 4; ++g)
                dst[(size_t)(rowb + g) * sd + cc] = f2bf(acc[mf][nf][g] + bv);
        }
    }
}

// ---------- MFMA GEMM 128x128 (round-10 structure; used for proj) ----------
template <bool OUT_F32>
__global__ __launch_bounds__(256) void mfma_gemm_kernel(
    const unsigned short* __restrict__ A, int lda,
    const unsigned short* __restrict__ Wt,
    const float* __restrict__ bias,
    void* __restrict__ dst0, int sd0,
    void* __restrict__ dst1, int sd1, int ncut,
    int K)
{
    __shared__ unsigned short As[2][128 * 32];
    __shared__ unsigned short Bs[2][128 * 32];
    const int BUFSZ = 128 * 32;

    const int t    = threadIdx.x;
    const int m0   = blockIdx.y * 128;
    const int n0   = blockIdx.x * 128;
    const int lane = t & 63, wave = t >> 6;
    const int quad = lane >> 4, l15 = lane & 15;
    const int mw   = (wave >> 1) * 64;
    const int nw   = (wave & 1) * 64;

    f32x4 acc[4][4];
#pragma unroll
    for (int i = 0; i < 4; ++i)
#pragma unroll
        for (int j = 0; j < 4; ++j) acc[i][j] = (f32x4){0.f, 0.f, 0.f, 0.f};

    const int srow  = lane >> 2;          // 0..15
    const int sslot = (lane & 3) * 8;     // shorts

    const unsigned short* gA0 = A  + (size_t)(m0 + wave * 32 + srow) * lda + sslot;
    const unsigned short* gA1 = gA0 + (size_t)16 * lda;
    const unsigned short* gB0 = Wt + (size_t)(n0 + wave * 32 + srow) * K + sslot;
    const unsigned short* gB1 = gB0 + (size_t)16 * K;
    unsigned short* lA0 = &As[0][(wave * 32) * 32];
    unsigned short* lA1 = lA0 + 16 * 32;
    unsigned short* lB0 = &Bs[0][(wave * 32) * 32];
    unsigned short* lB1 = lB0 + 16 * 32;

    gload_lds16(gA0, lA0);
    gload_lds16(gA1, lA1);
    gload_lds16(gB0, lB0);
    gload_lds16(gB1, lB1);
    __syncthreads();

    int cur = 0;
    for (int k0 = 0; k0 < K; k0 += 32) {
        const int nxt = cur ^ 1;
        if (k0 + 32 < K) {
            gload_lds16(gA0 + k0 + 32, lA0 + nxt * BUFSZ);
            gload_lds16(gA1 + k0 + 32, lA1 + nxt * BUFSZ);
            gload_lds16(gB0 + k0 + 32, lB0 + nxt * BUFSZ);
            gload_lds16(gB1 + k0 + 32, lB1 + nxt * BUFSZ);
        }

        const unsigned short* rA = &As[cur][0];
        const unsigned short* rB = &Bs[cur][0];
        bf16x8 af[4], bfr[4];
#pragma unroll
        for (int i = 0; i < 4; ++i)
            af[i] = *(const bf16x8*)&rA[(mw + i * 16 + l15) * 32 + quad * 8];
#pragma unroll
        for (int j = 0; j < 4; ++j)
            bfr[j] = *(const bf16x8*)&rB[(nw + j * 16 + l15) * 32 + quad * 8];
#pragma unroll
        for (int i = 0; i < 4; ++i)
#pragma unroll
            for (int j = 0; j < 4; ++j)
                acc[i][j] = __builtin_amdgcn_mfma_f32_16x16x32_bf16(af[i], bfr[j], acc[i][j], 0, 0, 0);

        __syncthreads();
        cur = nxt;
    }

#pragma unroll
    for (int j = 0; j < 4; ++j) {
        const int col = n0 + nw + j * 16 + l15;
        const float bv = bias[col];
        if (OUT_F32) {
            float* dst = (float*)dst0;
#pragma unroll
            for (int i = 0; i < 4; ++i) {
                const int rowb = m0 + mw + i * 16 + quad * 4;
#pragma unroll
                for (int g = 0; g < 4; ++g)
                    dst[(size_t)(rowb + g) * sd0 + col] = acc[i][j][g] + bv;
            }
        } else {
            unsigned short* dst; int sd, cc;
            if (col < ncut) { dst = (unsigned short*)dst0; sd = sd0; cc = col; }
            else            { dst = (unsigned short*)dst1; sd = sd1; cc = col - ncut; }
#pragma unroll
            for (int i = 0; i < 4; ++i) {
                const int rowb = m0 + mw + i * 16 + quad * 4;
#pragma unroll
                for (int g = 0; g < 4; ++g)
                    dst[(size_t)(rowb + g) * sd + cc] = f2bf(acc[i][j][g] + bv);
            }
        }
    }
}

// ---------- MFMA fused attention (round-11 version, unchanged) ----------
__global__ __launch_bounds__(256, 2) void attn_mfma_kernel(
    unsigned short* __restrict__ qk,         // [2048][5120] bf16: Q [0,2560), K [2560,5120)
    const unsigned short* __restrict__ vsrc, // [2048][2560] bf16 (parked in d_out)
    const float* __restrict__ gmats,
    const float* __restrict__ gphases,
    const float* __restrict__ gamps,
    const float* __restrict__ qphase,
    const float* __restrict__ is_ptr)
{
    __shared__ unsigned short Ks[64 * 104]; // Q tile (prologue) then K tiles; [row][d], pad d 80..96 = 0
    __shared__ unsigned short Vt[80 * 72];  // V^T [d][kj]
    __shared__ unsigned short Ps[64 * 72];  // P [q][kj] bf16
    __shared__ float cs[240];               // coeffs [3][80]

    const int t    = threadIdx.x;
    const int wave = t >> 6, lane = t & 63;
    const int quad = lane >> 4, l15 = lane & 15;
    // bijective XCD swizzle over 1024 blocks (8 XCDs x 128 chunks)
    const int lin0 = blockIdx.x;
    const int lin  = ((lin0 & 7) << 7) | (lin0 >> 3);
    const int qt = lin & 15;
    const int bh = lin >> 4;
    const int h  = bh & 31;
    const int b  = bh >> 5;

    const float scale = 0.111803398874989485f;   // 1/sqrt(80)
    const float c2    = scale * scale * is_ptr[0] * (1.0f / 3.0f);
    const float cosph = cosf(qphase[h]);

    if (t < 240) {
        int g = t / 80;
        float r0 = gmats[g*4+0] + gmats[g*4+1];
        float r1 = gmats[g*4+2] + gmats[g*4+3];
        cs[t] = (cosf(gphases[t]) * r0 + sinf(gphases[t]) * r1) * gamps[t];
    }

    const int srow = t >> 2;          // staging row 0..63 (wave w stages rows 16w..16w+15)
    const int scg  = (t & 3) * 20;    // staging col group (20 bf16)

    // V staging mapping (kg-inner, conflict-reduced):
    const int vkg  = t & 15;
    const int vdg0 = t >> 4;

    {   // stage Q tile into Ks + zero the d-pad [80,96)
        const unsigned short* qp = qk + (size_t)(b * S_ + qt * 64 + srow) * QK_ + h * D_ + scg;
#pragma unroll
        for (int u = 0; u < 5; ++u)
            *(ushort4*)&Ks[srow * 104 + scg + 4 * u] = *(const ushort4*)(qp + 4 * u);
        *(ushort4*)&Ks[srow * 104 + 80 + (t & 3) * 4] = (ushort4){0, 0, 0, 0};
    }
    __syncthreads();   // cs + Q visible

    // ---- prefetch tile 0 into registers (overlaps afq/afg build) ----
    ushort4 kpre[5];
    ushort4 vpre[8];
    {
        const unsigned short* kp = qk + (size_t)(b * S_ + srow) * QK_ + E_ + h * D_ + scg;
#pragma unroll
        for (int u = 0; u < 5; ++u) kpre[u] = *(const ushort4*)(kp + 4 * u);
        const unsigned short* vb = vsrc + (size_t)(b * S_) * E_ + h * D_;
#pragma unroll
        for (int i = 0; i < 4; ++i)
            vpre[i] = *(const ushort4*)(vb + (size_t)(vkg * 4 + i) * E_ + vdg0 * 4);
        if (t < 64) {
#pragma unroll
            for (int i = 0; i < 4; ++i)
                vpre[4 + i] = *(const ushort4*)(vb + (size_t)(vkg * 4 + i) * E_ + 64 + vdg0 * 4);
        }
    }

    // A-fragments: base Q + 3 coefficient-scaled variants (persist across k-tiles)
    bf16x8 afq[3], afg[3][3];
#pragma unroll
    for (int kc = 0; kc < 3; ++kc)
        afq[kc] = *(const bf16x8*)&Ks[(wave * 16 + l15) * 104 + quad * 8 + kc * 32];
#pragma unroll
    for (int g = 0; g < 3; ++g)
#pragma unroll
        for (int kc = 0; kc < 3; ++kc)
#pragma unroll
            for (int j = 0; j < 8; ++j) {
                int d = kc * 32 + quad * 8 + j;
                float c = (d < 80) ? cs[g * 80 + d] : 0.f;
                afg[g][kc][j] = (short)f2bf(bf2f((unsigned short)afq[kc][j]) * c);
            }

    f32x4 Ov[5];
#pragma unroll
    for (int nf = 0; nf < 5; ++nf) Ov[nf] = (f32x4){0.f, 0.f, 0.f, 0.f};
    float m_r[4] = {-INFINITY, -INFINITY, -INFINITY, -INFINITY};
    float l_r[4] = {0.f, 0.f, 0.f, 0.f};

    for (int kt = 0; kt < 16; ++kt) {
        __syncthreads();   // prev iter's Ks/Vt/Ps reads complete (iter0: Q-frag reads done)

        // ---- write prefetched K tile [kj][d] into Ks (pad stays 0) ----
#pragma unroll
        for (int u = 0; u < 5; ++u)
            *(ushort4*)&Ks[srow * 104 + scg + 4 * u] = kpre[u];

        // ---- write prefetched V^T [d][kj] via 4x4 in-register transpose ----
        {
            const unsigned short rm[4][4] = {
                {vpre[0].x, vpre[0].y, vpre[0].z, vpre[0].w},
                {vpre[1].x, vpre[1].y, vpre[1].z, vpre[1].w},
                {vpre[2].x, vpre[2].y, vpre[2].z, vpre[2].w},
                {vpre[3].x, vpre[3].y, vpre[3].z, vpre[3].w}};
#pragma unroll
            for (int j = 0; j < 4; ++j) {
                ushort4 w = {rm[0][j], rm[1][j], rm[2][j], rm[3][j]};
                *(ushort4*)&Vt[(vdg0 * 4 + j) * 72 + vkg * 4] = w;
            }
        }
        if (t < 64) {
            const unsigned short rm[4][4] = {
                {vpre[4].x, vpre[4].y, vpre[4].z, vpre[4].w},
                {vpre[5].x, vpre[5].y, vpre[5].z, vpre[5].w},
                {vpre[6].x, vpre[6].y, vpre[6].z, vpre[6].w},
                {vpre[7].x, vpre[7].y, vpre[7].z, vpre[7].w}};
#pragma unroll
            for (int j = 0; j < 4; ++j) {
                ushort4 w = {rm[0][j], rm[1][j], rm[2][j], rm[3][j]};
                *(ushort4*)&Vt[(64 + vdg0 * 4 + j) * 72 + vkg * 4] = w;
            }
        }
        __syncthreads();

        // ---- issue next tile's global loads; latency hides under compute ----
        if (kt < 15) {
            const unsigned short* kp = qk + (size_t)(b * S_ + (kt + 1) * 64 + srow) * QK_ + E_ + h * D_ + scg;
#pragma unroll
            for (int u = 0; u < 5; ++u) kpre[u] = *(const ushort4*)(kp + 4 * u);
            const unsigned short* vb = vsrc + (size_t)(b * S_ + (kt + 1) * 64) * E_ + h * D_;
#pragma unroll
            for (int i = 0; i < 4; ++i)
                vpre[i] = *(const ushort4*)(vb + (size_t)(vkg * 4 + i) * E_ + vdg0 * 4);
            if (t < 64) {
#pragma unroll
                for (int i = 0; i < 4; ++i)
                    vpre[4 + i] = *(const ushort4*)(vb + (size_t)(vkg * 4 + i) * E_ + 64 + vdg0 * 4);
            }
        }

        // ---- score MFMAs in two nf-halves: only sacc[4][2] live at once ----
        float p[4][4];   // [nf][r]
        float mx[4] = {-INFINITY, -INFINITY, -INFINITY, -INFINITY};
#pragma unroll
        for (int hf = 0; hf < 2; ++hf) {
            f32x4 sacc[4][2];
#pragma unroll
            for (int v = 0; v < 4; ++v)
#pragma unroll
                for (int n = 0; n < 2; ++n) sacc[v][n] = (f32x4){0.f, 0.f, 0.f, 0.f};
#pragma unroll
            for (int kc = 0; kc < 3; ++kc) {
                bf16x8 bk[2];
#pragma unroll
                for (int n = 0; n < 2; ++n)
                    bk[n] = *(const bf16x8*)&Ks[((hf * 2 + n) * 16 + l15) * 104 + quad * 8 + kc * 32];
#pragma unroll
                for (int n = 0; n < 2; ++n)
                    sacc[0][n] = __builtin_amdgcn_mfma_f32_16x16x32_bf16(afq[kc], bk[n], sacc[0][n], 0, 0, 0);
#pragma unroll
                for (int g = 0; g < 3; ++g)
#pragma unroll
                    for (int n = 0; n < 2; ++n)
                        sacc[1+g][n] = __builtin_amdgcn_mfma_f32_16x16x32_bf16(afg[g][kc], bk[n], sacc[1+g][n], 0, 0, 0);
            }
#pragma unroll
            for (int n = 0; n < 2; ++n)
#pragma unroll
                for (int r = 0; r < 4; ++r) {
                    float s0 = sacc[1][n][r], s1 = sacc[2][n][r], s2 = sacc[3][n][r];
                    float s = fmaf(fmaf(s0, s1, (s0 + s1) * s2), c2, sacc[0][n][r] * scale);
                    p[hf * 2 + n][r] = s;
                    mx[r] = fmaxf(mx[r], s);
                }
        }

        // ---- online softmax (C layout: row=quad*4+r, col=l15+16nf) ----
#pragma unroll
        for (int r = 0; r < 4; ++r) {
            mx[r] = fmaxf(mx[r], __shfl_xor(mx[r], 1));
            mx[r] = fmaxf(mx[r], __shfl_xor(mx[r], 2));
            mx[r] = fmaxf(mx[r], __shfl_xor(mx[r], 4));
            mx[r] = fmaxf(mx[r], __shfl_xor(mx[r], 8));
        }
        float alpha[4];
#pragma unroll
        for (int r = 0; r < 4; ++r) {
            float m_new = fmaxf(m_r[r], mx[r]);
            alpha[r] = __expf(m_r[r] - m_new);
            m_r[r] = m_new;
        }
#pragma unroll
        for (int nf = 0; nf < 4; ++nf)
#pragma unroll
            for (int r = 0; r < 4; ++r)
                p[nf][r] = __expf(p[nf][r] - m_r[r]);
#pragma unroll
        for (int r = 0; r < 4; ++r) {
            float s = p[0][r] + p[1][r] + p[2][r] + p[3][r];
            s += __shfl_xor(s, 1);
            s += __shfl_xor(s, 2);
            s += __shfl_xor(s, 4);
            s += __shfl_xor(s, 8);
            l_r[r] = l_r[r] * alpha[r] + s;
        }

        // ---- write P (bf16) to LDS; own-wave rows only ----
#pragma unroll
        for (int nf = 0; nf < 4; ++nf)
#pragma unroll
            for (int r = 0; r < 4; ++r)
                Ps[(wave * 16 + quad * 4 + r) * 72 + l15 + 16 * nf] = f2bf(p[nf][r]);
        __asm__ volatile("s_waitcnt lgkmcnt(0)" ::: "memory");

        // ---- O rescale + PV MFMAs ----
#pragma unroll
        for (int nf = 0; nf < 5; ++nf)
#pragma unroll
            for (int r = 0; r < 4; ++r) Ov[nf][r] *= alpha[r];

        bf16x8 ap[2];
#pragma unroll
        for (int kc = 0; kc < 2; ++kc)
            ap[kc] = *(const bf16x8*)&Ps[(wave * 16 + l15) * 72 + quad * 8 + kc * 32];
#pragma unroll
        for (int nf = 0; nf < 5; ++nf)
#pragma unroll
            for (int kc = 0; kc < 2; ++kc) {
                bf16x8 bv = *(const bf16x8*)&Vt[(nf * 16 + l15) * 72 + quad * 8 + kc * 32];
                Ov[nf] = __builtin_amdgcn_mfma_f32_16x16x32_bf16(ap[kc], bv, Ov[nf], 0, 0, 0);
            }
    }

    // ---- epilogue: O * cos(phase)/l -> Q section of qk (bf16) ----
    float inv[4];
#pragma unroll
    for (int r = 0; r < 4; ++r) inv[r] = cosph / l_r[r];
#pragma unroll
    for (int nf = 0; nf < 5; ++nf)
#pragma unroll
        for (int r = 0; r < 4; ++r)
            qk[(size_t)(b * S_ + qt * 64 + wave * 16 + quad * 4 + r) * QK_ + h * D_ + nf * 16 + l15]
                = f2bf(Ov[nf][r] * inv[r]);
}

extern "C" void kernel_launch(void* const* d_in, const int* in_sizes, int n_in,
                              void* d_out, int out_size, void* d_ws, size_t ws_size,
                              hipStream_t stream) {
    (void)in_sizes; (void)n_in; (void)out_size; (void)ws_size;
    const float* hidden  = (const float*)d_in[0];
    const float* Wqkv    = (const float*)d_in[1];
    const float* bqkv    = (const float*)d_in[2];
    const float* Wproj   = (const float*)d_in[3];
    const float* bproj   = (const float*)d_in[4];
    const float* gmats   = (const float*)d_in[5];
    const float* gphases = (const float*)d_in[6];
    const float* gamps   = (const float*)d_in[7];
    const float* qphase  = (const float*)d_in[8];
    const float* is_ptr  = (const float*)d_in[9];

    // ws layout (70.8 MB): qk_ws 21.0 MB | h_bf16 10.5 MB | Wt 39.3 MB (reused for Wproj_t)
    unsigned short* qk_ws  = (unsigned short*)d_ws;
    unsigned short* h_bf16 = (unsigned short*)((char*)d_ws + (size_t)M_ * QK_ * 2);
    unsigned short* Wt     = (unsigned short*)((char*)d_ws + (size_t)M_ * QK_ * 2 + (size_t)M_ * E_ * 2);
    unsigned short* v_buf  = (unsigned short*)d_out;   // V bf16 parked in d_out (consumed by attn)

    dim3 blk(256);
    cvt_bf16_kernel<<<dim3((M_ * E_ / 8 + 255) / 256), blk, 0, stream>>>(hidden, h_bf16, M_ * E_ / 8);
    transpose_bf16_kernel<<<dim3(E3_/64, E_/64), blk, 0, stream>>>(Wqkv, Wt, E_, E3_);
    mfma_gemm256_kernel<<<dim3(E3_/256, M_/256), dim3(512), 0, stream>>>(
        h_bf16, E_, Wt, bqkv, qk_ws, QK_, v_buf, E_, QK_, E_);
    attn_mfma_kernel<<<dim3(2 * H_ * (S_/64)), blk, 0, stream>>>(
        qk_ws, v_buf, gmats, gphases, gamps, qphase, is_ptr);
    transpose_bf16_kernel<<<dim3(E_/64, E_/64), blk, 0, stream>>>(Wproj, Wt, E_, E_);
    mfma_gemm_kernel<true><<<dim3(E_/128, M_/128), blk, 0, stream>>>(
        qk_ws, QK_, Wt, bproj, d_out, E_, d_out, E_, E_, E_);
}